// Round 7
// baseline (1898.610 us; speedup 1.0000x reference)
//
#include <hip/hip_runtime.h>
#include <hip/hip_bf16.h>
#include <cstdint>

// butterfly: all lanes end with the full 64-lane sum
__device__ __forceinline__ float wave_sum_all(float v){
#pragma unroll
  for (int o = 32; o > 0; o >>= 1) v += __shfl_xor(v, o, 64);
  return v;
}
__device__ __forceinline__ float wave_sum(float v){
#pragma unroll
  for (int o = 32; o > 0; o >>= 1) v += __shfl_down(v, o, 64);
  return v;  // lane 0 holds the sum
}

// ---- copy f32 [n,64] -> f32 strided [n, stride] ----
__global__ void k_copy_in(const float* __restrict__ src, float* __restrict__ dst,
                          int n, int stride){
  int idx = blockIdx.x * 256 + threadIdx.x;
  if (idx >= n * 64) return;
  int r = idx >> 6, j = idx & 63;
  dst[(size_t)r * stride + j] = src[idx];
}

// ---- out[n,64] = x[n, xo:xo+64] @ W(64x64) + b ----
// W held in 64 VGPRs per lane (lane j = column j); one wave per row,
// x broadcast via shfl. Replaces the LDS version (2 ds_reads per FMA).
__global__ void k_linear(const float* __restrict__ x, int xs, int xo,
                         const float* __restrict__ W, const float* __restrict__ b,
                         float* __restrict__ out, int n){
  int j = threadIdx.x & 63;
  int gw = blockIdx.x * 4 + (threadIdx.x >> 6);   // global wave id
  int nw = gridDim.x * 4;
  float Wreg[64];
#pragma unroll
  for (int k = 0; k < 64; ++k) Wreg[k] = W[k * 64 + j];
  float bj = b[j];
  for (int row = gw; row < n; row += nw){
    float xv = x[(size_t)row * xs + xo + j];
    float acc0 = 0.f, acc1 = 0.f;
#pragma unroll
    for (int k = 0; k < 32; ++k){
      acc0 += __shfl(xv, 2 * k,     64) * Wreg[2 * k];
      acc1 += __shfl(xv, 2 * k + 1, 64) * Wreg[2 * k + 1];
    }
    out[(size_t)row * 64 + j] = bj + acc0 + acc1;
  }
}

// ================= CSR build (per call; ws is re-poisoned) =================
__global__ void k_hist(const int* __restrict__ dst, int* __restrict__ cnt, int E){
  int k = blockIdx.x * 256 + threadIdx.x;
  if (k < E) atomicAdd(cnt + dst[k], 1);
}
// fused: both groupings of the rate edge list in one pass
__global__ void k_hist2(const int* __restrict__ src, const int* __restrict__ dst,
                        int* __restrict__ cntA, int* __restrict__ cntB, int E){
  int k = blockIdx.x * 256 + threadIdx.x;
  if (k >= E) return;
  atomicAdd(cntA + dst[k], 1);
  atomicAdd(cntB + src[k], 1);
}

// multi-block scan: each block allocates a contiguous range for its 1024-chunk
// via atomicAdd on gbase. Offsets are disjoint but NOT globally monotone ->
// consumers use cnt[] for segment ends (each segment itself is contiguous).
__global__ void k_scan_mb(const int* __restrict__ cnt, int n,
                          int* __restrict__ offs, int* __restrict__ cur,
                          int* __restrict__ gbase){
  __shared__ int wsum[16];
  __shared__ int base_sh;
  int t = threadIdx.x, lane = t & 63, w = t >> 6;
  int i = blockIdx.x * 1024 + t;
  int v = (i < n) ? cnt[i] : 0;
  int x = v;                       // inclusive scan within wave
#pragma unroll
  for (int o = 1; o < 64; o <<= 1){
    int y = __shfl_up(x, o, 64);
    if (lane >= o) x += y;
  }
  if (lane == 63) wsum[w] = x;
  __syncthreads();
  if (t == 0){
    int tot = 0;
    for (int k = 0; k < 16; ++k){ int c = wsum[k]; wsum[k] = tot; tot += c; }
    base_sh = atomicAdd(gbase, tot);
  }
  __syncthreads();
  if (i < n){
    int e = base_sh + wsum[w] + x - v;
    offs[i] = e; cur[i] = e;
  }
}

__global__ void k_csr_fill(const int* __restrict__ src, const int* __restrict__ dst,
                           int* __restrict__ cur, int* __restrict__ csr_src, int E){
  int k = blockIdx.x * 256 + threadIdx.x;
  if (k >= E) return;
  int pos = atomicAdd(cur + dst[k], 1);
  csr_src[pos] = src[k];
}
// fused: fill both rate CSRs in one pass over the edge list
__global__ void k_csr_fill2(const int* __restrict__ src, const int* __restrict__ dst,
                            int* __restrict__ curA, int* __restrict__ csrA,
                            int* __restrict__ curB, int* __restrict__ csrB, int E){
  int k = blockIdx.x * 256 + threadIdx.x;
  if (k >= E) return;
  int s = src[k], d = dst[k];
  int pa = atomicAdd(curA + d, 1);
  csrA[pa] = s;
  int pb = atomicAdd(curB + s, 1);
  csrB[pb] = d;
}

// ============ fused GATv2 aggregation: one wave per dst node ============
// masked 4-way: no serial tail (invalid slots reuse slot-0's index and get
// their exp-weight zeroed; indices stay in-bounds, values stay finite).
__global__ void k_gat(const int* __restrict__ offs, const int* __restrict__ cnt,
                      const int* __restrict__ csr_src,
                      const float* __restrict__ fs, const float* __restrict__ fd,
                      const float* __restrict__ attn, const float* __restrict__ bias,
                      float* __restrict__ out, int os, int oo,
                      const float* __restrict__ res, int rs, int ro, int n){
  int d = blockIdx.x * 4 + (threadIdx.x >> 6);
  if (d >= n) return;
  int j = threadIdx.x & 63;
  float fdv = fd[(size_t)d * 64 + j];
  float aj  = attn[j];
  float acc = 0.f, den = 0.f;
  int idx = offs[d], end = idx + cnt[d];
  for (; idx < end; idx += 4){
    int s0 = csr_src[idx];
    bool m1 = idx + 1 < end, m2 = idx + 2 < end, m3 = idx + 3 < end;
    int s1 = m1 ? csr_src[idx + 1] : s0;
    int s2 = m2 ? csr_src[idx + 2] : s0;
    int s3 = m3 ? csr_src[idx + 3] : s0;
    float f0 = fs[(size_t)s0 * 64 + j], f1 = fs[(size_t)s1 * 64 + j],
          f2 = fs[(size_t)s2 * 64 + j], f3 = fs[(size_t)s3 * 64 + j];
    float v0 = f0 + fdv; v0 = (v0 > 0.f ? v0 : 0.2f * v0) * aj;
    float v1 = f1 + fdv; v1 = (v1 > 0.f ? v1 : 0.2f * v1) * aj;
    float v2 = f2 + fdv; v2 = (v2 > 0.f ? v2 : 0.2f * v2) * aj;
    float v3 = f3 + fdv; v3 = (v3 > 0.f ? v3 : 0.2f * v3) * aj;
#pragma unroll
    for (int o = 32; o > 0; o >>= 1){
      v0 += __shfl_xor(v0, o, 64); v1 += __shfl_xor(v1, o, 64);
      v2 += __shfl_xor(v2, o, 64); v3 += __shfl_xor(v3, o, 64);
    }
    float ex0 = __expf(v0);
    float ex1 = m1 ? __expf(v1) : 0.f;
    float ex2 = m2 ? __expf(v2) : 0.f;
    float ex3 = m3 ? __expf(v3) : 0.f;
    acc += ex0 * f0; acc += ex1 * f1; acc += ex2 * f2; acc += ex3 * f3;
    den += (ex0 + ex1) + (ex2 + ex3);
  }
  float o = (den > 0.f) ? acc / den : 0.f;   // empty segment -> bias only
  o += bias[j];
  if (res) o += res[(size_t)d * rs + ro + j];
  out[(size_t)d * os + oo + j] = o;
}

// ---- collapse attention-gate MLP: v = W1@W2 (per l,i), c = b1@W2 + b2 ----
__global__ void k_attvec(const float* __restrict__ W1, const float* __restrict__ b1,
                         const float* __restrict__ W2, const float* __restrict__ b2,
                         float* __restrict__ vvec, float* __restrict__ cs){
  int t = threadIdx.x;           // 512 threads: (l*2+i) in [0,4), r in [0,128)
  int li = t >> 7, r = t & 127;
  float acc = 0.f;
  for (int c = 0; c < 128; ++c)
    acc += W1[(size_t)(li * 128 + r) * 128 + c] * W2[li * 128 + c];
  vvec[li * 128 + r] = acc;
  if (r == 0){
    float cacc = b2[li];
    for (int c = 0; c < 128; ++c)
      cacc += b1[li * 128 + c] * W2[li * 128 + c];
    cs[li] = cacc;
  }
}

// ---- gate z-scores + per-block partial sums for BatchNorm ----
__global__ void k_gate_z(const float* __restrict__ hu_all, int l,
                         const float* __restrict__ p, const float* __restrict__ q,
                         const float* __restrict__ vvec, const float* __restrict__ cs,
                         float* __restrict__ z1, float* __restrict__ z2,
                         float* __restrict__ bsums, int n){
  __shared__ float part[4][4];
  int w = threadIdx.x >> 6, j = threadIdx.x & 63;
  int nidx = blockIdx.x * 4 + w;
  float lz1 = 0.f, lz2 = 0.f;
  if (nidx < n){
    const float* v1 = vvec + l * 256;
    const float* v2 = vvec + l * 256 + 128;
    float h  = hu_all[(size_t)nidx * 192 + l * 64 + j];
    float pv = p[(size_t)nidx * 64 + j];
    float qv = q[(size_t)nidx * 64 + j];
    float t1 = wave_sum(h * v1[j] + pv * v1[64 + j]);
    float t2 = wave_sum(h * v2[j] + qv * v2[64 + j]);
    if (j == 0){
      lz1 = t1 + cs[l * 2 + 0];
      lz2 = t2 + cs[l * 2 + 1];
      z1[nidx] = lz1;
      z2[nidx] = lz2;
    }
  }
  if (j == 0){
    part[w][0] = lz1; part[w][1] = lz1 * lz1;
    part[w][2] = lz2; part[w][3] = lz2 * lz2;
  }
  __syncthreads();
  if (threadIdx.x < 4)
    bsums[(size_t)blockIdx.x * 4 + threadIdx.x] =
        part[0][threadIdx.x] + part[1][threadIdx.x] +
        part[2][threadIdx.x] + part[3][threadIdx.x];
}

// ---- BN reduce stage 1: 128 blocks grid-stride over bsums -> gpart[128][4] ----
__global__ void k_bn_part(const float* __restrict__ bsums, int nb,
                          double* __restrict__ gpart){
  __shared__ double sh[256];
  int c = threadIdx.x & 3, r0 = blockIdx.x * 64 + (threadIdx.x >> 2);
  double acc = 0.0;
  for (int i = r0; i < nb; i += gridDim.x * 64)
    acc += (double)bsums[(size_t)i * 4 + c];
  sh[threadIdx.x] = acc;
  __syncthreads();
  for (int s = 128; s >= 4; s >>= 1){
    if (threadIdx.x < s) sh[threadIdx.x] += sh[threadIdx.x + s];
    __syncthreads();
  }
  if (threadIdx.x < 4) gpart[(size_t)blockIdx.x * 4 + threadIdx.x] = sh[threadIdx.x];
}

// ---- BN reduce stage 2: single block over 128 partials -> sums[4] ----
__global__ void k_bn_final(const double* __restrict__ gpart, int nbk,
                           double* __restrict__ sums){
  __shared__ double sh[256];
  int c = threadIdx.x & 3, k0 = threadIdx.x >> 2;
  double acc = 0.0;
  for (int i = k0; i < nbk; i += 64) acc += gpart[(size_t)i * 4 + c];
  sh[threadIdx.x] = acc;
  __syncthreads();
  for (int s = 128; s >= 4; s >>= 1){
    if (threadIdx.x < s) sh[threadIdx.x] += sh[threadIdx.x + s];
    __syncthreads();
  }
  if (threadIdx.x < 4) sums[threadIdx.x] = sh[threadIdx.x];
}

// ---- BN + lrelu(0.01) + softmax gate + residual combine -> hu_all block l+1 ----
__global__ void k_gate_combine(float* __restrict__ hu_all, int l,
                               const float* __restrict__ p, const float* __restrict__ q,
                               const float* __restrict__ z1, const float* __restrict__ z2,
                               const double* __restrict__ sums, int n){
  int idx = blockIdx.x * 256 + threadIdx.x;
  if (idx >= n * 64) return;
  int r = idx >> 6, j = idx & 63;
  double invn = 1.0 / (double)n;
  double mu1 = sums[0] * invn, mu2 = sums[2] * invn;
  float var1 = (float)(sums[1] * invn - mu1 * mu1);
  float var2 = (float)(sums[3] * invn - mu2 * mu2);
  float rs1 = rsqrtf(var1 + 1e-5f), rs2 = rsqrtf(var2 + 1e-5f);
  float a1 = (z1[r] - (float)mu1) * rs1;
  float a2 = (z2[r] - (float)mu2) * rs2;
  a1 = a1 > 0.f ? a1 : 0.01f * a1;
  a2 = a2 > 0.f ? a2 : 0.01f * a2;
  float mx = fmaxf(a1, a2);
  float e1 = __expf(a1 - mx), e2 = __expf(a2 - mx);
  float inv = 1.f / (e1 + e2);
  float out = (e1 * inv) * p[idx] + (e2 * inv) * q[idx]
            + hu_all[(size_t)r * 192 + l * 64 + j];
  hu_all[(size_t)r * 192 + (l + 1) * 64 + j] = out;
}

// ---- final scoring: 2 pairs per wave (32 lanes each), float2 loads ----
__global__ void k_score(const int* __restrict__ pu, const int* __restrict__ pi,
                        const int* __restrict__ nu, const int* __restrict__ ni,
                        const float* __restrict__ hu_all, const float* __restrict__ hi_all,
                        float* __restrict__ out, int EP){
  int gw = blockIdx.x * 4 + (threadIdx.x >> 6);
  int half = (threadIdx.x >> 5) & 1, l32 = threadIdx.x & 31;
  int k = gw * 2 + half;
  if (k >= 2 * EP) return;
  int u, i;
  if (k < EP){ u = pu[k]; i = pi[k]; } else { u = nu[k - EP]; i = ni[k - EP]; }
  const float2* hu = (const float2*)(hu_all + (size_t)u * 192);
  const float2* hi = (const float2*)(hi_all + (size_t)i * 192);
  float acc = 0.f;
#pragma unroll
  for (int t = 0; t < 3; ++t){
    float2 a = hu[l32 + 32 * t];
    float2 b = hi[l32 + 32 * t];
    acc += a.x * b.x + a.y * b.y;
  }
#pragma unroll
  for (int o = 16; o > 0; o >>= 1) acc += __shfl_xor(acc, o, 64);
  if (l32 == 0) out[k] = acc;
}

extern "C" void kernel_launch(void* const* d_in, const int* in_sizes, int n_in,
                              void* d_out, int out_size, void* d_ws, size_t ws_size,
                              hipStream_t stream) {
  const int*   rate_src  = (const int*)  d_in[0];
  const int*   rate_dst  = (const int*)  d_in[1];
  const int*   trust_src = (const int*)  d_in[2];
  const int*   trust_dst = (const int*)  d_in[3];
  const int*   pos_u     = (const int*)  d_in[4];
  const int*   pos_i     = (const int*)  d_in[5];
  const int*   neg_u     = (const int*)  d_in[6];
  const int*   neg_i     = (const int*)  d_in[7];
  const float* eu        = (const float*)d_in[8];
  const float* ei        = (const float*)d_in[9];
  const float* rate_W    = (const float*)d_in[10];
  const float* rate_b    = (const float*)d_in[11];
  const float* rate_attn = (const float*)d_in[12];
  const float* rate_bias = (const float*)d_in[13];
  const float* rb_W      = (const float*)d_in[14];
  const float* rb_b      = (const float*)d_in[15];
  const float* rb_attn   = (const float*)d_in[16];
  const float* rb_bias   = (const float*)d_in[17];
  const float* tr_W      = (const float*)d_in[18];
  const float* tr_b      = (const float*)d_in[19];
  const float* tr_attn   = (const float*)d_in[20];
  const float* tr_bias   = (const float*)d_in[21];
  const float* attW1     = (const float*)d_in[22];
  const float* attb1     = (const float*)d_in[23];
  const float* attW2     = (const float*)d_in[24];
  const float* attb2     = (const float*)d_in[25];

  const int ER = in_sizes[0];
  const int ET = in_sizes[2];
  const int EP = in_sizes[4];
  const int NU = in_sizes[8] / 64;
  const int NI = in_sizes[9] / 64;

  // ---- workspace layout: f32 region then int region ----
  float* ws = (float*)d_ws;
  float*  hu_all = ws;                                   // NU*192
  float*  hi_all = hu_all + (size_t)NU * 192;            // NI*192
  float*  p      = hi_all + (size_t)NI * 192;            // NU*64
  float*  q      = p + (size_t)NU * 64;                  // NU*64
  float*  fs     = q + (size_t)NU * 64;                  // NU*64
  float*  fd     = fs + (size_t)NU * 64;                 // NU*64
  float*  z1     = fd + (size_t)NU * 64;                 // NU
  float*  z2     = z1 + NU;                              // NU
  float*  bsums  = z2 + NU;                              // cdiv(NU,4)*4
  float*  vvec   = bsums + (size_t)(((NU + 3) / 4) * 4); // 512
  float*  cs     = vvec + 512;                           // 4
  double* sums   = (double*)(((uintptr_t)(cs + 4) + 15) & ~(uintptr_t)15); // 4
  double* gpart  = sums + 4;           // 128*4 doubles
  int*    iw     = (int*)(gpart + 512);
  int*    cntA   = iw;                 // NI
  int*    cntB   = cntA + NI;          // NU
  int*    cntC   = cntB + NU;          // NU
  int*    gbase  = cntC + NU;          // 4 (3 used)
  int*    offsA  = gbase + 4;          // NI
  int*    curA   = offsA + NI;         // NI
  int*    offsB  = curA + NI;          // NU
  int*    curB   = offsB + NU;         // NU
  int*    offsC  = curB + NU;          // NU
  int*    curC   = offsC + NU;         // NU
  int*    csrA   = curC + NU;          // ER (user srcs, grouped by item)
  int*    csrB   = csrA + ER;          // ER (item srcs, grouped by user)
  int*    csrC   = csrB + ER;          // ET (user srcs, grouped by dst user)

  auto cdiv = [](int a, int b){ return (a + b - 1) / b; };
  const int nbz = cdiv(NU, 4);

  // ---- one-time per call: init state + gate MLP collapse + CSR builds ----
  k_copy_in<<<cdiv(NU * 64, 256), 256, 0, stream>>>(eu, hu_all, NU, 192);
  k_copy_in<<<cdiv(NI * 64, 256), 256, 0, stream>>>(ei, hi_all, NI, 192);
  k_attvec<<<1, 512, 0, stream>>>(attW1, attb1, attW2, attb2, vvec, cs);

  hipMemsetAsync(cntA, 0, (size_t)(NI + 2 * NU + 4) * 4, stream);
  k_hist2<<<cdiv(ER, 256), 256, 0, stream>>>(rate_src, rate_dst, cntA, cntB, ER);
  k_hist<<<cdiv(ET, 256), 256, 0, stream>>>(trust_dst, cntC, ET);
  k_scan_mb<<<cdiv(NI, 1024), 1024, 0, stream>>>(cntA, NI, offsA, curA, gbase + 0);
  k_scan_mb<<<cdiv(NU, 1024), 1024, 0, stream>>>(cntB, NU, offsB, curB, gbase + 1);
  k_scan_mb<<<cdiv(NU, 1024), 1024, 0, stream>>>(cntC, NU, offsC, curC, gbase + 2);
  k_csr_fill2<<<cdiv(ER, 256), 256, 0, stream>>>(rate_src, rate_dst,
      curA, csrA, curB, csrB, ER);
  k_csr_fill<<<cdiv(ET, 256), 256, 0, stream>>>(trust_src, trust_dst, curC, csrC, ET);

  for (int l = 0; l < 2; ++l){
    // ---------- rate GAT: users -> items, into hi_all block l+1 (+bias+residual) ----------
    k_linear<<<1024, 256, 0, stream>>>(hu_all, 192, l * 64,
        rate_W + (size_t)(l * 2 + 0) * 4096, rate_b + (l * 2 + 0) * 64, fs, NU);
    k_linear<<<1024, 256, 0, stream>>>(hi_all, 192, l * 64,
        rate_W + (size_t)(l * 2 + 1) * 4096, rate_b + (l * 2 + 1) * 64, fd, NI);
    k_gat<<<cdiv(NI, 4), 256, 0, stream>>>(offsA, cntA, csrA, fs, fd,
        rate_attn + l * 64, rate_bias + l * 64,
        hi_all, 192, (l + 1) * 64, hi_all, 192, l * 64, NI);

    // ---------- rated-by GAT: items -> users, result q ----------
    k_linear<<<1024, 256, 0, stream>>>(hi_all, 192, l * 64,
        rb_W + (size_t)(l * 2 + 0) * 4096, rb_b + (l * 2 + 0) * 64, fs, NI);
    k_linear<<<1024, 256, 0, stream>>>(hu_all, 192, l * 64,
        rb_W + (size_t)(l * 2 + 1) * 4096, rb_b + (l * 2 + 1) * 64, fd, NU);
    k_gat<<<cdiv(NU, 4), 256, 0, stream>>>(offsB, cntB, csrB, fs, fd,
        rb_attn + l * 64, rb_bias + l * 64,
        q, 64, 0, (const float*)nullptr, 0, 0, NU);

    // ---------- trust GAT: users -> users, result p ----------
    k_linear<<<1024, 256, 0, stream>>>(hu_all, 192, l * 64,
        tr_W + (size_t)(l * 2 + 0) * 4096, tr_b + (l * 2 + 0) * 64, fs, NU);
    k_linear<<<1024, 256, 0, stream>>>(hu_all, 192, l * 64,
        tr_W + (size_t)(l * 2 + 1) * 4096, tr_b + (l * 2 + 1) * 64, fd, NU);
    k_gat<<<cdiv(NU, 4), 256, 0, stream>>>(offsC, cntC, csrC, fs, fd,
        tr_attn + l * 64, tr_bias + l * 64,
        p, 64, 0, (const float*)nullptr, 0, 0, NU);

    // ---------- attention gate + combine -> hu_all block l+1 ----------
    k_gate_z<<<nbz, 256, 0, stream>>>(hu_all, l, p, q, vvec, cs, z1, z2, bsums, NU);
    k_bn_part<<<128, 256, 0, stream>>>(bsums, nbz, gpart);
    k_bn_final<<<1, 256, 0, stream>>>(gpart, 128, sums);
    k_gate_combine<<<cdiv(NU * 64, 256), 256, 0, stream>>>(hu_all, l, p, q, z1, z2, sums, NU);
  }

  // ---------- final scoring ----------
  k_score<<<cdiv(2 * EP, 8), 256, 0, stream>>>(pos_u, pos_i, neg_u, neg_i,
      hu_all, hi_all, (float*)d_out, EP);
}

// Round 8
// 1300.967 us; speedup vs baseline: 1.4594x; 1.4594x over previous
//
#include <hip/hip_runtime.h>
#include <hip/hip_bf16.h>
#include <cstdint>

typedef __attribute__((ext_vector_type(8))) short frag_ab;   // 8 bf16 (4 VGPRs)
typedef __attribute__((ext_vector_type(4))) float frag_cd;   // 4 fp32

// split f32 into hi/lo bf16 bit patterns (x ~= hi + lo, rel err ~2^-17)
__device__ __forceinline__ void bf_split(float x, short& hi, short& lo){
  __hip_bfloat16 h = __float2bfloat16(x);
  float hf = __bfloat162float(h);
  __hip_bfloat16 l = __float2bfloat16(x - hf);
  __builtin_memcpy(&hi, &h, 2);
  __builtin_memcpy(&lo, &l, 2);
}

// butterfly: all lanes end with the full 64-lane sum
__device__ __forceinline__ float wave_sum(float v){
#pragma unroll
  for (int o = 32; o > 0; o >>= 1) v += __shfl_down(v, o, 64);
  return v;  // lane 0 holds the sum
}

// ---- copy f32 [n,64] -> f32 strided [n, stride] ----
__global__ void k_copy_in(const float* __restrict__ src, float* __restrict__ dst,
                          int n, int stride){
  int idx = blockIdx.x * 256 + threadIdx.x;
  if (idx >= n * 64) return;
  int r = idx >> 6, j = idx & 63;
  dst[(size_t)r * stride + j] = src[idx];
}

// ---- out[n,64] = x[n, xo:xo+64] @ W(64x64) + b  via split-bf16 MFMA ----
// block = 256 thr = 4 waves; wave w handles rows [blk*64 + w*16, +16).
// Per wave: 4 col-tiles (16 wide), K=64 as 2 halves, 3 MFMAs per (tile,half):
// ahi*bhi + alo*bhi + ahi*blo  (lo*lo term ~2^-18, dropped).
__global__ void k_linear(const float* __restrict__ x, int xs, int xo,
                         const float* __restrict__ W, const float* __restrict__ b,
                         float* __restrict__ out, int n){
  __shared__ float Wl[4096];
  int t = threadIdx.x;
  for (int i = t; i < 4096; i += 256) Wl[i] = W[i];
  __syncthreads();
  int lane = t & 63, w = t >> 6;
  int quad = lane >> 4, n16 = lane & 15;

  // B fragments: lane holds B[k = 32h + quad*8 + j][col = 16c + n16]
  frag_ab bhi[4][2], blo[4][2];
#pragma unroll
  for (int c = 0; c < 4; ++c)
#pragma unroll
    for (int h = 0; h < 2; ++h){
      frag_ab vh, vl;
#pragma unroll
      for (int j = 0; j < 8; ++j){
        float wv = Wl[(32 * h + quad * 8 + j) * 64 + 16 * c + n16];
        short sh, sl; bf_split(wv, sh, sl);
        vh[j] = sh; vl[j] = sl;
      }
      bhi[c][h] = vh; blo[c][h] = vl;
    }
  float bj[4];
#pragma unroll
  for (int c = 0; c < 4; ++c) bj[c] = b[16 * c + n16];

  int rowbase = blockIdx.x * 64 + w * 16;
  if (rowbase >= n) return;
  // A fragments: lane holds A[m = n16][k = 32h + quad*8 + j]
  int lrow = rowbase + n16; if (lrow >= n) lrow = n - 1;   // clamp (stores guarded)
  const float* xp = x + (size_t)lrow * xs + xo;
  frag_ab ahi[2], alo[2];
#pragma unroll
  for (int h = 0; h < 2; ++h){
    frag_ab vh, vl;
#pragma unroll
    for (int j = 0; j < 8; ++j){
      float xv = xp[32 * h + quad * 8 + j];
      short sh, sl; bf_split(xv, sh, sl);
      vh[j] = sh; vl[j] = sl;
    }
    ahi[h] = vh; alo[h] = vl;
  }
  frag_cd acc[4];
#pragma unroll
  for (int c = 0; c < 4; ++c) acc[c] = frag_cd{0.f, 0.f, 0.f, 0.f};
#pragma unroll
  for (int c = 0; c < 4; ++c)
#pragma unroll
    for (int h = 0; h < 2; ++h){
      acc[c] = __builtin_amdgcn_mfma_f32_16x16x32_bf16(ahi[h], bhi[c][h], acc[c], 0, 0, 0);
      acc[c] = __builtin_amdgcn_mfma_f32_16x16x32_bf16(alo[h], bhi[c][h], acc[c], 0, 0, 0);
      acc[c] = __builtin_amdgcn_mfma_f32_16x16x32_bf16(ahi[h], blo[c][h], acc[c], 0, 0, 0);
    }
  // D: col = 16c + n16, row = rowbase + quad*4 + reg
#pragma unroll
  for (int reg = 0; reg < 4; ++reg){
    int r = rowbase + quad * 4 + reg;
    if (r >= n) continue;
#pragma unroll
    for (int c = 0; c < 4; ++c)
      out[(size_t)r * 64 + 16 * c + n16] = acc[c][reg] + bj[c];
  }
}

// ================= CSR build (per call; ws is re-poisoned) =================
__global__ void k_hist(const int* __restrict__ dst, int* __restrict__ cnt, int E){
  int k = blockIdx.x * 256 + threadIdx.x;
  if (k < E) atomicAdd(cnt + dst[k], 1);
}
__global__ void k_hist2(const int* __restrict__ src, const int* __restrict__ dst,
                        int* __restrict__ cntA, int* __restrict__ cntB, int E){
  int k = blockIdx.x * 256 + threadIdx.x;
  if (k >= E) return;
  atomicAdd(cntA + dst[k], 1);
  atomicAdd(cntB + src[k], 1);
}

// multi-block scan: block grabs contiguous range via atomicAdd on gbase.
// Offsets disjoint but not globally monotone -> consumers use cnt[] for ends.
__global__ void k_scan_mb(const int* __restrict__ cnt, int n,
                          int* __restrict__ offs, int* __restrict__ cur,
                          int* __restrict__ gbase){
  __shared__ int wsum[16];
  __shared__ int base_sh;
  int t = threadIdx.x, lane = t & 63, w = t >> 6;
  int i = blockIdx.x * 1024 + t;
  int v = (i < n) ? cnt[i] : 0;
  int x = v;
#pragma unroll
  for (int o = 1; o < 64; o <<= 1){
    int y = __shfl_up(x, o, 64);
    if (lane >= o) x += y;
  }
  if (lane == 63) wsum[w] = x;
  __syncthreads();
  if (t == 0){
    int tot = 0;
    for (int k = 0; k < 16; ++k){ int c = wsum[k]; wsum[k] = tot; tot += c; }
    base_sh = atomicAdd(gbase, tot);
  }
  __syncthreads();
  if (i < n){
    int e = base_sh + wsum[w] + x - v;
    offs[i] = e; cur[i] = e;
  }
}

__global__ void k_csr_fill(const int* __restrict__ src, const int* __restrict__ dst,
                           int* __restrict__ cur, int* __restrict__ csr_src, int E){
  int k = blockIdx.x * 256 + threadIdx.x;
  if (k >= E) return;
  int pos = atomicAdd(cur + dst[k], 1);
  csr_src[pos] = src[k];
}
__global__ void k_csr_fill2(const int* __restrict__ src, const int* __restrict__ dst,
                            int* __restrict__ curA, int* __restrict__ csrA,
                            int* __restrict__ curB, int* __restrict__ csrB, int E){
  int k = blockIdx.x * 256 + threadIdx.x;
  if (k >= E) return;
  int s = src[k], d = dst[k];
  int pa = atomicAdd(curA + d, 1);
  csrA[pa] = s;
  int pb = atomicAdd(curB + s, 1);
  csrB[pb] = d;
}

// ============ fused GATv2 aggregation: one wave per dst node ============
__global__ void k_gat(const int* __restrict__ offs, const int* __restrict__ cnt,
                      const int* __restrict__ csr_src,
                      const float* __restrict__ fs, const float* __restrict__ fd,
                      const float* __restrict__ attn, const float* __restrict__ bias,
                      float* __restrict__ out, int os, int oo,
                      const float* __restrict__ res, int rs, int ro, int n){
  int d = blockIdx.x * 4 + (threadIdx.x >> 6);
  if (d >= n) return;
  int j = threadIdx.x & 63;
  float fdv = fd[(size_t)d * 64 + j];
  float aj  = attn[j];
  float acc = 0.f, den = 0.f;
  int idx = offs[d], end = idx + cnt[d];
  for (; idx < end; idx += 4){
    int s0 = csr_src[idx];
    bool m1 = idx + 1 < end, m2 = idx + 2 < end, m3 = idx + 3 < end;
    int s1 = m1 ? csr_src[idx + 1] : s0;
    int s2 = m2 ? csr_src[idx + 2] : s0;
    int s3 = m3 ? csr_src[idx + 3] : s0;
    float f0 = fs[(size_t)s0 * 64 + j], f1 = fs[(size_t)s1 * 64 + j],
          f2 = fs[(size_t)s2 * 64 + j], f3 = fs[(size_t)s3 * 64 + j];
    float v0 = f0 + fdv; v0 = (v0 > 0.f ? v0 : 0.2f * v0) * aj;
    float v1 = f1 + fdv; v1 = (v1 > 0.f ? v1 : 0.2f * v1) * aj;
    float v2 = f2 + fdv; v2 = (v2 > 0.f ? v2 : 0.2f * v2) * aj;
    float v3 = f3 + fdv; v3 = (v3 > 0.f ? v3 : 0.2f * v3) * aj;
#pragma unroll
    for (int o = 32; o > 0; o >>= 1){
      v0 += __shfl_xor(v0, o, 64); v1 += __shfl_xor(v1, o, 64);
      v2 += __shfl_xor(v2, o, 64); v3 += __shfl_xor(v3, o, 64);
    }
    float ex0 = __expf(v0);
    float ex1 = m1 ? __expf(v1) : 0.f;
    float ex2 = m2 ? __expf(v2) : 0.f;
    float ex3 = m3 ? __expf(v3) : 0.f;
    acc += ex0 * f0; acc += ex1 * f1; acc += ex2 * f2; acc += ex3 * f3;
    den += (ex0 + ex1) + (ex2 + ex3);
  }
  float o = (den > 0.f) ? acc / den : 0.f;
  o += bias[j];
  if (res) o += res[(size_t)d * rs + ro + j];
  out[(size_t)d * os + oo + j] = o;
}

// ---- collapse attention-gate MLP: v = W1@W2 (per l,i), c = b1@W2 + b2 ----
__global__ void k_attvec(const float* __restrict__ W1, const float* __restrict__ b1,
                         const float* __restrict__ W2, const float* __restrict__ b2,
                         float* __restrict__ vvec, float* __restrict__ cs){
  int t = threadIdx.x;
  int li = t >> 7, r = t & 127;
  float acc = 0.f;
  for (int c = 0; c < 128; ++c)
    acc += W1[(size_t)(li * 128 + r) * 128 + c] * W2[li * 128 + c];
  vvec[li * 128 + r] = acc;
  if (r == 0){
    float cacc = b2[li];
    for (int c = 0; c < 128; ++c)
      cacc += b1[li * 128 + c] * W2[li * 128 + c];
    cs[li] = cacc;
  }
}

// ---- gate z-scores + per-block partial sums for BatchNorm ----
__global__ void k_gate_z(const float* __restrict__ hu_all, int l,
                         const float* __restrict__ p, const float* __restrict__ q,
                         const float* __restrict__ vvec, const float* __restrict__ cs,
                         float* __restrict__ z1, float* __restrict__ z2,
                         float* __restrict__ bsums, int n){
  __shared__ float part[4][4];
  int w = threadIdx.x >> 6, j = threadIdx.x & 63;
  int nidx = blockIdx.x * 4 + w;
  float lz1 = 0.f, lz2 = 0.f;
  if (nidx < n){
    const float* v1 = vvec + l * 256;
    const float* v2 = vvec + l * 256 + 128;
    float h  = hu_all[(size_t)nidx * 192 + l * 64 + j];
    float pv = p[(size_t)nidx * 64 + j];
    float qv = q[(size_t)nidx * 64 + j];
    float t1 = wave_sum(h * v1[j] + pv * v1[64 + j]);
    float t2 = wave_sum(h * v2[j] + qv * v2[64 + j]);
    if (j == 0){
      lz1 = t1 + cs[l * 2 + 0];
      lz2 = t2 + cs[l * 2 + 1];
      z1[nidx] = lz1;
      z2[nidx] = lz2;
    }
  }
  if (j == 0){
    part[w][0] = lz1; part[w][1] = lz1 * lz1;
    part[w][2] = lz2; part[w][3] = lz2 * lz2;
  }
  __syncthreads();
  if (threadIdx.x < 4)
    bsums[(size_t)blockIdx.x * 4 + threadIdx.x] =
        part[0][threadIdx.x] + part[1][threadIdx.x] +
        part[2][threadIdx.x] + part[3][threadIdx.x];
}

// ---- BN reduce stage 1: 128 blocks grid-stride -> gpart[128][4] ----
__global__ void k_bn_part(const float* __restrict__ bsums, int nb,
                          double* __restrict__ gpart){
  __shared__ double sh[256];
  int c = threadIdx.x & 3, r0 = blockIdx.x * 64 + (threadIdx.x >> 2);
  double acc = 0.0;
  for (int i = r0; i < nb; i += gridDim.x * 64)
    acc += (double)bsums[(size_t)i * 4 + c];
  sh[threadIdx.x] = acc;
  __syncthreads();
  for (int s = 128; s >= 4; s >>= 1){
    if (threadIdx.x < s) sh[threadIdx.x] += sh[threadIdx.x + s];
    __syncthreads();
  }
  if (threadIdx.x < 4) gpart[(size_t)blockIdx.x * 4 + threadIdx.x] = sh[threadIdx.x];
}

// ---- BN reduce stage 2: single block over 128 partials -> sums[4] ----
__global__ void k_bn_final(const double* __restrict__ gpart, int nbk,
                           double* __restrict__ sums){
  __shared__ double sh[256];
  int c = threadIdx.x & 3, k0 = threadIdx.x >> 2;
  double acc = 0.0;
  for (int i = k0; i < nbk; i += 64) acc += gpart[(size_t)i * 4 + c];
  sh[threadIdx.x] = acc;
  __syncthreads();
  for (int s = 128; s >= 4; s >>= 1){
    if (threadIdx.x < s) sh[threadIdx.x] += sh[threadIdx.x + s];
    __syncthreads();
  }
  if (threadIdx.x < 4) sums[threadIdx.x] = sh[threadIdx.x];
}

// ---- BN + lrelu(0.01) + softmax gate + residual combine ----
__global__ void k_gate_combine(float* __restrict__ hu_all, int l,
                               const float* __restrict__ p, const float* __restrict__ q,
                               const float* __restrict__ z1, const float* __restrict__ z2,
                               const double* __restrict__ sums, int n){
  int idx = blockIdx.x * 256 + threadIdx.x;
  if (idx >= n * 64) return;
  int r = idx >> 6, j = idx & 63;
  double invn = 1.0 / (double)n;
  double mu1 = sums[0] * invn, mu2 = sums[2] * invn;
  float var1 = (float)(sums[1] * invn - mu1 * mu1);
  float var2 = (float)(sums[3] * invn - mu2 * mu2);
  float rs1 = rsqrtf(var1 + 1e-5f), rs2 = rsqrtf(var2 + 1e-5f);
  float a1 = (z1[r] - (float)mu1) * rs1;
  float a2 = (z2[r] - (float)mu2) * rs2;
  a1 = a1 > 0.f ? a1 : 0.01f * a1;
  a2 = a2 > 0.f ? a2 : 0.01f * a2;
  float mx = fmaxf(a1, a2);
  float e1 = __expf(a1 - mx), e2 = __expf(a2 - mx);
  float inv = 1.f / (e1 + e2);
  float out = (e1 * inv) * p[idx] + (e2 * inv) * q[idx]
            + hu_all[(size_t)r * 192 + l * 64 + j];
  hu_all[(size_t)r * 192 + (l + 1) * 64 + j] = out;
}

// ---- final scoring: 2 pairs per wave (32 lanes each), float2 loads ----
__global__ void k_score(const int* __restrict__ pu, const int* __restrict__ pi,
                        const int* __restrict__ nu, const int* __restrict__ ni,
                        const float* __restrict__ hu_all, const float* __restrict__ hi_all,
                        float* __restrict__ out, int EP){
  int gw = blockIdx.x * 4 + (threadIdx.x >> 6);
  int half = (threadIdx.x >> 5) & 1, l32 = threadIdx.x & 31;
  int k = gw * 2 + half;
  if (k >= 2 * EP) return;
  int u, i;
  if (k < EP){ u = pu[k]; i = pi[k]; } else { u = nu[k - EP]; i = ni[k - EP]; }
  const float2* hu = (const float2*)(hu_all + (size_t)u * 192);
  const float2* hi = (const float2*)(hi_all + (size_t)i * 192);
  float acc = 0.f;
#pragma unroll
  for (int t = 0; t < 3; ++t){
    float2 a = hu[l32 + 32 * t];
    float2 b = hi[l32 + 32 * t];
    acc += a.x * b.x + a.y * b.y;
  }
#pragma unroll
  for (int o = 16; o > 0; o >>= 1) acc += __shfl_xor(acc, o, 64);
  if (l32 == 0) out[k] = acc;
}

extern "C" void kernel_launch(void* const* d_in, const int* in_sizes, int n_in,
                              void* d_out, int out_size, void* d_ws, size_t ws_size,
                              hipStream_t stream) {
  const int*   rate_src  = (const int*)  d_in[0];
  const int*   rate_dst  = (const int*)  d_in[1];
  const int*   trust_src = (const int*)  d_in[2];
  const int*   trust_dst = (const int*)  d_in[3];
  const int*   pos_u     = (const int*)  d_in[4];
  const int*   pos_i     = (const int*)  d_in[5];
  const int*   neg_u     = (const int*)  d_in[6];
  const int*   neg_i     = (const int*)  d_in[7];
  const float* eu        = (const float*)d_in[8];
  const float* ei        = (const float*)d_in[9];
  const float* rate_W    = (const float*)d_in[10];
  const float* rate_b    = (const float*)d_in[11];
  const float* rate_attn = (const float*)d_in[12];
  const float* rate_bias = (const float*)d_in[13];
  const float* rb_W      = (const float*)d_in[14];
  const float* rb_b      = (const float*)d_in[15];
  const float* rb_attn   = (const float*)d_in[16];
  const float* rb_bias   = (const float*)d_in[17];
  const float* tr_W      = (const float*)d_in[18];
  const float* tr_b      = (const float*)d_in[19];
  const float* tr_attn   = (const float*)d_in[20];
  const float* tr_bias   = (const float*)d_in[21];
  const float* attW1     = (const float*)d_in[22];
  const float* attb1     = (const float*)d_in[23];
  const float* attW2     = (const float*)d_in[24];
  const float* attb2     = (const float*)d_in[25];

  const int ER = in_sizes[0];
  const int ET = in_sizes[2];
  const int EP = in_sizes[4];
  const int NU = in_sizes[8] / 64;
  const int NI = in_sizes[9] / 64;

  // ---- workspace layout: f32 region then int region ----
  float* ws = (float*)d_ws;
  float*  hu_all = ws;                                   // NU*192
  float*  hi_all = hu_all + (size_t)NU * 192;            // NI*192
  float*  p      = hi_all + (size_t)NI * 192;            // NU*64
  float*  q      = p + (size_t)NU * 64;                  // NU*64
  float*  fs     = q + (size_t)NU * 64;                  // NU*64
  float*  fd     = fs + (size_t)NU * 64;                 // NU*64
  float*  z1     = fd + (size_t)NU * 64;                 // NU
  float*  z2     = z1 + NU;                              // NU
  float*  bsums  = z2 + NU;                              // cdiv(NU,4)*4
  float*  vvec   = bsums + (size_t)(((NU + 3) / 4) * 4); // 512
  float*  cs     = vvec + 512;                           // 4
  double* sums   = (double*)(((uintptr_t)(cs + 4) + 15) & ~(uintptr_t)15); // 4
  double* gpart  = sums + 4;           // 128*4 doubles
  int*    iw     = (int*)(gpart + 512);
  int*    cntA   = iw;                 // NI
  int*    cntB   = cntA + NI;          // NU
  int*    cntC   = cntB + NU;          // NU
  int*    gbase  = cntC + NU;          // 4 (3 used)
  int*    offsA  = gbase + 4;          // NI
  int*    curA   = offsA + NI;         // NI
  int*    offsB  = curA + NI;          // NU
  int*    curB   = offsB + NU;         // NU
  int*    offsC  = curB + NU;          // NU
  int*    curC   = offsC + NU;         // NU
  int*    csrA   = curC + NU;          // ER (user srcs, grouped by item)
  int*    csrB   = csrA + ER;          // ER (item srcs, grouped by user)
  int*    csrC   = csrB + ER;          // ET (user srcs, grouped by dst user)

  auto cdiv = [](int a, int b){ return (a + b - 1) / b; };
  const int nbz = cdiv(NU, 4);

  // ---- one-time per call: init state + gate MLP collapse + CSR builds ----
  k_copy_in<<<cdiv(NU * 64, 256), 256, 0, stream>>>(eu, hu_all, NU, 192);
  k_copy_in<<<cdiv(NI * 64, 256), 256, 0, stream>>>(ei, hi_all, NI, 192);
  k_attvec<<<1, 512, 0, stream>>>(attW1, attb1, attW2, attb2, vvec, cs);

  hipMemsetAsync(cntA, 0, (size_t)(NI + 2 * NU + 4) * 4, stream);
  k_hist2<<<cdiv(ER, 256), 256, 0, stream>>>(rate_src, rate_dst, cntA, cntB, ER);
  k_hist<<<cdiv(ET, 256), 256, 0, stream>>>(trust_dst, cntC, ET);
  k_scan_mb<<<cdiv(NI, 1024), 1024, 0, stream>>>(cntA, NI, offsA, curA, gbase + 0);
  k_scan_mb<<<cdiv(NU, 1024), 1024, 0, stream>>>(cntB, NU, offsB, curB, gbase + 1);
  k_scan_mb<<<cdiv(NU, 1024), 1024, 0, stream>>>(cntC, NU, offsC, curC, gbase + 2);
  k_csr_fill2<<<cdiv(ER, 256), 256, 0, stream>>>(rate_src, rate_dst,
      curA, csrA, curB, csrB, ER);
  k_csr_fill<<<cdiv(ET, 256), 256, 0, stream>>>(trust_src, trust_dst, curC, csrC, ET);

  for (int l = 0; l < 2; ++l){
    // ---------- rate GAT: users -> items, into hi_all block l+1 (+bias+residual) ----------
    k_linear<<<cdiv(NU, 64), 256, 0, stream>>>(hu_all, 192, l * 64,
        rate_W + (size_t)(l * 2 + 0) * 4096, rate_b + (l * 2 + 0) * 64, fs, NU);
    k_linear<<<cdiv(NI, 64), 256, 0, stream>>>(hi_all, 192, l * 64,
        rate_W + (size_t)(l * 2 + 1) * 4096, rate_b + (l * 2 + 1) * 64, fd, NI);
    k_gat<<<cdiv(NI, 4), 256, 0, stream>>>(offsA, cntA, csrA, fs, fd,
        rate_attn + l * 64, rate_bias + l * 64,
        hi_all, 192, (l + 1) * 64, hi_all, 192, l * 64, NI);

    // ---------- rated-by GAT: items -> users, result q ----------
    k_linear<<<cdiv(NI, 64), 256, 0, stream>>>(hi_all, 192, l * 64,
        rb_W + (size_t)(l * 2 + 0) * 4096, rb_b + (l * 2 + 0) * 64, fs, NI);
    k_linear<<<cdiv(NU, 64), 256, 0, stream>>>(hu_all, 192, l * 64,
        rb_W + (size_t)(l * 2 + 1) * 4096, rb_b + (l * 2 + 1) * 64, fd, NU);
    k_gat<<<cdiv(NU, 4), 256, 0, stream>>>(offsB, cntB, csrB, fs, fd,
        rb_attn + l * 64, rb_bias + l * 64,
        q, 64, 0, (const float*)nullptr, 0, 0, NU);

    // ---------- trust GAT: users -> users, result p ----------
    k_linear<<<cdiv(NU, 64), 256, 0, stream>>>(hu_all, 192, l * 64,
        tr_W + (size_t)(l * 2 + 0) * 4096, tr_b + (l * 2 + 0) * 64, fs, NU);
    k_linear<<<cdiv(NU, 64), 256, 0, stream>>>(hu_all, 192, l * 64,
        tr_W + (size_t)(l * 2 + 1) * 4096, tr_b + (l * 2 + 1) * 64, fd, NU);
    k_gat<<<cdiv(NU, 4), 256, 0, stream>>>(offsC, cntC, csrC, fs, fd,
        tr_attn + l * 64, tr_bias + l * 64,
        p, 64, 0, (const float*)nullptr, 0, 0, NU);

    // ---------- attention gate + combine -> hu_all block l+1 ----------
    k_gate_z<<<nbz, 256, 0, stream>>>(hu_all, l, p, q, vvec, cs, z1, z2, bsums, NU);
    k_bn_part<<<128, 256, 0, stream>>>(bsums, nbz, gpart);
    k_bn_final<<<1, 256, 0, stream>>>(gpart, 128, sums);
    k_gate_combine<<<cdiv(NU * 64, 256), 256, 0, stream>>>(hu_all, l, p, q, z1, z2, sums, NU);
  }

  // ---------- final scoring ----------
  k_score<<<cdiv(2 * EP, 8), 256, 0, stream>>>(pos_u, pos_i, neg_u, neg_i,
      hu_all, hi_all, (float*)d_out, EP);
}

// Round 9
// 1267.089 us; speedup vs baseline: 1.4984x; 1.0267x over previous
//
#include <hip/hip_runtime.h>
#include <hip/hip_bf16.h>
#include <cstdint>

typedef __hip_bfloat16 bf16;
typedef __attribute__((ext_vector_type(8))) short frag_ab;   // 8 bf16 (4 VGPRs)
typedef __attribute__((ext_vector_type(4))) float frag_cd;   // 4 fp32

// split f32 into hi/lo bf16 bit patterns (x ~= hi + lo, rel err ~2^-17)
__device__ __forceinline__ void bf_split(float x, short& hi, short& lo){
  bf16 h = __float2bfloat16(x);
  float hf = __bfloat162float(h);
  bf16 l = __float2bfloat16(x - hf);
  __builtin_memcpy(&hi, &h, 2);
  __builtin_memcpy(&lo, &l, 2);
}

__device__ __forceinline__ float wave_sum(float v){
#pragma unroll
  for (int o = 32; o > 0; o >>= 1) v += __shfl_down(v, o, 64);
  return v;  // lane 0 holds the sum
}

// ---- copy f32 [n,64] -> f32 strided [n, stride] ----
__global__ void k_copy_in(const float* __restrict__ src, float* __restrict__ dst,
                          int n, int stride){
  int idx = blockIdx.x * 256 + threadIdx.x;
  if (idx >= n * 64) return;
  int r = idx >> 6, j = idx & 63;
  dst[(size_t)r * stride + j] = src[idx];
}

// ---- out_bf[n,64] = bf16( x[n, xo:xo+64] @ W(64x64) + b )  via split-bf16 MFMA ----
// block = 256 thr = 4 waves; wave w handles rows [blk*64 + w*16, +16).
__global__ void k_linear(const float* __restrict__ x, int xs, int xo,
                         const float* __restrict__ W, const float* __restrict__ b,
                         bf16* __restrict__ out, int n){
  __shared__ float Wl[4096];
  int t = threadIdx.x;
  for (int i = t; i < 4096; i += 256) Wl[i] = W[i];
  __syncthreads();
  int lane = t & 63, w = t >> 6;
  int quad = lane >> 4, n16 = lane & 15;

  // B fragments: lane holds B[k = 32h + quad*8 + j][col = 16c + n16]
  frag_ab bhi[4][2], blo[4][2];
#pragma unroll
  for (int c = 0; c < 4; ++c)
#pragma unroll
    for (int h = 0; h < 2; ++h){
      frag_ab vh, vl;
#pragma unroll
      for (int j = 0; j < 8; ++j){
        float wv = Wl[(32 * h + quad * 8 + j) * 64 + 16 * c + n16];
        short sh, sl; bf_split(wv, sh, sl);
        vh[j] = sh; vl[j] = sl;
      }
      bhi[c][h] = vh; blo[c][h] = vl;
    }
  float bj[4];
#pragma unroll
  for (int c = 0; c < 4; ++c) bj[c] = b[16 * c + n16];

  int rowbase = blockIdx.x * 64 + w * 16;
  if (rowbase >= n) return;
  int lrow = rowbase + n16; if (lrow >= n) lrow = n - 1;   // clamp (stores guarded)
  const float* xp = x + (size_t)lrow * xs + xo;
  frag_ab ahi[2], alo[2];
#pragma unroll
  for (int h = 0; h < 2; ++h){
    frag_ab vh, vl;
#pragma unroll
    for (int j = 0; j < 8; ++j){
      float xv = xp[32 * h + quad * 8 + j];
      short sh, sl; bf_split(xv, sh, sl);
      vh[j] = sh; vl[j] = sl;
    }
    ahi[h] = vh; alo[h] = vl;
  }
  frag_cd acc[4];
#pragma unroll
  for (int c = 0; c < 4; ++c) acc[c] = frag_cd{0.f, 0.f, 0.f, 0.f};
#pragma unroll
  for (int c = 0; c < 4; ++c)
#pragma unroll
    for (int h = 0; h < 2; ++h){
      acc[c] = __builtin_amdgcn_mfma_f32_16x16x32_bf16(ahi[h], bhi[c][h], acc[c], 0, 0, 0);
      acc[c] = __builtin_amdgcn_mfma_f32_16x16x32_bf16(alo[h], bhi[c][h], acc[c], 0, 0, 0);
      acc[c] = __builtin_amdgcn_mfma_f32_16x16x32_bf16(ahi[h], blo[c][h], acc[c], 0, 0, 0);
    }
  // D: col = 16c + n16, row = rowbase + quad*4 + reg
#pragma unroll
  for (int reg = 0; reg < 4; ++reg){
    int r = rowbase + quad * 4 + reg;
    if (r >= n) continue;
#pragma unroll
    for (int c = 0; c < 4; ++c)
      out[(size_t)r * 64 + 16 * c + n16] = __float2bfloat16(acc[c][reg] + bj[c]);
  }
}

// ================= CSR build (per call; ws is re-poisoned) =================
__global__ void k_hist(const int* __restrict__ dst, int* __restrict__ cnt, int E){
  int k = blockIdx.x * 256 + threadIdx.x;
  if (k < E) atomicAdd(cnt + dst[k], 1);
}
__global__ void k_hist2(const int* __restrict__ src, const int* __restrict__ dst,
                        int* __restrict__ cntA, int* __restrict__ cntB, int E){
  int k = blockIdx.x * 256 + threadIdx.x;
  if (k >= E) return;
  atomicAdd(cntA + dst[k], 1);
  atomicAdd(cntB + src[k], 1);
}

// multi-block scan: block grabs contiguous range via atomicAdd on gbase.
// Offsets disjoint but not globally monotone -> consumers use cnt[] for ends.
__global__ void k_scan_mb(const int* __restrict__ cnt, int n,
                          int* __restrict__ offs, int* __restrict__ cur,
                          int* __restrict__ gbase){
  __shared__ int wsum[16];
  __shared__ int base_sh;
  int t = threadIdx.x, lane = t & 63, w = t >> 6;
  int i = blockIdx.x * 1024 + t;
  int v = (i < n) ? cnt[i] : 0;
  int x = v;
#pragma unroll
  for (int o = 1; o < 64; o <<= 1){
    int y = __shfl_up(x, o, 64);
    if (lane >= o) x += y;
  }
  if (lane == 63) wsum[w] = x;
  __syncthreads();
  if (t == 0){
    int tot = 0;
    for (int k = 0; k < 16; ++k){ int c = wsum[k]; wsum[k] = tot; tot += c; }
    base_sh = atomicAdd(gbase, tot);
  }
  __syncthreads();
  if (i < n){
    int e = base_sh + wsum[w] + x - v;
    offs[i] = e; cur[i] = e;
  }
}

__global__ void k_csr_fill(const int* __restrict__ src, const int* __restrict__ dst,
                           int* __restrict__ cur, int* __restrict__ csr_src, int E){
  int k = blockIdx.x * 256 + threadIdx.x;
  if (k >= E) return;
  int pos = atomicAdd(cur + dst[k], 1);
  csr_src[pos] = src[k];
}
__global__ void k_csr_fill2(const int* __restrict__ src, const int* __restrict__ dst,
                            int* __restrict__ curA, int* __restrict__ csrA,
                            int* __restrict__ curB, int* __restrict__ csrB, int E){
  int k = blockIdx.x * 256 + threadIdx.x;
  if (k >= E) return;
  int s = src[k], d = dst[k];
  int pa = atomicAdd(curA + d, 1);
  csrA[pa] = s;
  int pb = atomicAdd(curB + s, 1);
  csrB[pb] = d;
}

// ============ fused GATv2 aggregation: one wave per dst node ============
// fs/fd tables are bf16 (halves MALL gather traffic); math in f32.
__global__ void k_gat(const int* __restrict__ offs, const int* __restrict__ cnt,
                      const int* __restrict__ csr_src,
                      const bf16* __restrict__ fs, const bf16* __restrict__ fd,
                      const float* __restrict__ attn, const float* __restrict__ bias,
                      float* __restrict__ out, int os, int oo,
                      const float* __restrict__ res, int rs, int ro, int n){
  int d = blockIdx.x * 4 + (threadIdx.x >> 6);
  if (d >= n) return;
  int j = threadIdx.x & 63;
  float fdv = __bfloat162float(fd[(size_t)d * 64 + j]);
  float aj  = attn[j];
  float acc = 0.f, den = 0.f;
  int idx = offs[d], end = idx + cnt[d];
  for (; idx < end; idx += 4){
    int s0 = csr_src[idx];
    bool m1 = idx + 1 < end, m2 = idx + 2 < end, m3 = idx + 3 < end;
    int s1 = m1 ? csr_src[idx + 1] : s0;
    int s2 = m2 ? csr_src[idx + 2] : s0;
    int s3 = m3 ? csr_src[idx + 3] : s0;
    float f0 = __bfloat162float(fs[(size_t)s0 * 64 + j]);
    float f1 = __bfloat162float(fs[(size_t)s1 * 64 + j]);
    float f2 = __bfloat162float(fs[(size_t)s2 * 64 + j]);
    float f3 = __bfloat162float(fs[(size_t)s3 * 64 + j]);
    float v0 = f0 + fdv; v0 = (v0 > 0.f ? v0 : 0.2f * v0) * aj;
    float v1 = f1 + fdv; v1 = (v1 > 0.f ? v1 : 0.2f * v1) * aj;
    float v2 = f2 + fdv; v2 = (v2 > 0.f ? v2 : 0.2f * v2) * aj;
    float v3 = f3 + fdv; v3 = (v3 > 0.f ? v3 : 0.2f * v3) * aj;
#pragma unroll
    for (int o = 32; o > 0; o >>= 1){
      v0 += __shfl_xor(v0, o, 64); v1 += __shfl_xor(v1, o, 64);
      v2 += __shfl_xor(v2, o, 64); v3 += __shfl_xor(v3, o, 64);
    }
    float ex0 = __expf(v0);
    float ex1 = m1 ? __expf(v1) : 0.f;
    float ex2 = m2 ? __expf(v2) : 0.f;
    float ex3 = m3 ? __expf(v3) : 0.f;
    acc += ex0 * f0; acc += ex1 * f1; acc += ex2 * f2; acc += ex3 * f3;
    den += (ex0 + ex1) + (ex2 + ex3);
  }
  float o = (den > 0.f) ? acc / den : 0.f;
  o += bias[j];
  if (res) o += res[(size_t)d * rs + ro + j];
  out[(size_t)d * os + oo + j] = o;
}

// ---- collapse attention-gate MLP: v = W1@W2 (per l,i), c = b1@W2 + b2 ----
__global__ void k_attvec(const float* __restrict__ W1, const float* __restrict__ b1,
                         const float* __restrict__ W2, const float* __restrict__ b2,
                         float* __restrict__ vvec, float* __restrict__ cs){
  int t = threadIdx.x;
  int li = t >> 7, r = t & 127;
  float acc = 0.f;
  for (int c = 0; c < 128; ++c)
    acc += W1[(size_t)(li * 128 + r) * 128 + c] * W2[li * 128 + c];
  vvec[li * 128 + r] = acc;
  if (r == 0){
    float cacc = b2[li];
    for (int c = 0; c < 128; ++c)
      cacc += b1[li * 128 + c] * W2[li * 128 + c];
    cs[li] = cacc;
  }
}

// ---- gate z-scores + per-block partial sums for BatchNorm ----
__global__ void k_gate_z(const float* __restrict__ hu_all, int l,
                         const float* __restrict__ p, const float* __restrict__ q,
                         const float* __restrict__ vvec, const float* __restrict__ cs,
                         float* __restrict__ z1, float* __restrict__ z2,
                         float* __restrict__ bsums, int n){
  __shared__ float part[4][4];
  int w = threadIdx.x >> 6, j = threadIdx.x & 63;
  int nidx = blockIdx.x * 4 + w;
  float lz1 = 0.f, lz2 = 0.f;
  if (nidx < n){
    const float* v1 = vvec + l * 256;
    const float* v2 = vvec + l * 256 + 128;
    float h  = hu_all[(size_t)nidx * 192 + l * 64 + j];
    float pv = p[(size_t)nidx * 64 + j];
    float qv = q[(size_t)nidx * 64 + j];
    float t1 = wave_sum(h * v1[j] + pv * v1[64 + j]);
    float t2 = wave_sum(h * v2[j] + qv * v2[64 + j]);
    if (j == 0){
      lz1 = t1 + cs[l * 2 + 0];
      lz2 = t2 + cs[l * 2 + 1];
      z1[nidx] = lz1;
      z2[nidx] = lz2;
    }
  }
  if (j == 0){
    part[w][0] = lz1; part[w][1] = lz1 * lz1;
    part[w][2] = lz2; part[w][3] = lz2 * lz2;
  }
  __syncthreads();
  if (threadIdx.x < 4)
    bsums[(size_t)blockIdx.x * 4 + threadIdx.x] =
        part[0][threadIdx.x] + part[1][threadIdx.x] +
        part[2][threadIdx.x] + part[3][threadIdx.x];
}

// ---- BN reduce stage 1: 128 blocks grid-stride -> gpart[128][4] ----
__global__ void k_bn_part(const float* __restrict__ bsums, int nb,
                          double* __restrict__ gpart){
  __shared__ double sh[256];
  int c = threadIdx.x & 3, r0 = blockIdx.x * 64 + (threadIdx.x >> 2);
  double acc = 0.0;
  for (int i = r0; i < nb; i += gridDim.x * 64)
    acc += (double)bsums[(size_t)i * 4 + c];
  sh[threadIdx.x] = acc;
  __syncthreads();
  for (int s = 128; s >= 4; s >>= 1){
    if (threadIdx.x < s) sh[threadIdx.x] += sh[threadIdx.x + s];
    __syncthreads();
  }
  if (threadIdx.x < 4) gpart[(size_t)blockIdx.x * 4 + threadIdx.x] = sh[threadIdx.x];
}

// ---- BN reduce stage 2: single block over 128 partials -> sums[4] ----
__global__ void k_bn_final(const double* __restrict__ gpart, int nbk,
                           double* __restrict__ sums){
  __shared__ double sh[256];
  int c = threadIdx.x & 3, k0 = threadIdx.x >> 2;
  double acc = 0.0;
  for (int i = k0; i < nbk; i += 64) acc += gpart[(size_t)i * 4 + c];
  sh[threadIdx.x] = acc;
  __syncthreads();
  for (int s = 128; s >= 4; s >>= 1){
    if (threadIdx.x < s) sh[threadIdx.x] += sh[threadIdx.x + s];
    __syncthreads();
  }
  if (threadIdx.x < 4) sums[threadIdx.x] = sh[threadIdx.x];
}

// ---- BN + lrelu(0.01) + softmax gate + residual combine ----
__global__ void k_gate_combine(float* __restrict__ hu_all, int l,
                               const float* __restrict__ p, const float* __restrict__ q,
                               const float* __restrict__ z1, const float* __restrict__ z2,
                               const double* __restrict__ sums, int n){
  int idx = blockIdx.x * 256 + threadIdx.x;
  if (idx >= n * 64) return;
  int r = idx >> 6, j = idx & 63;
  double invn = 1.0 / (double)n;
  double mu1 = sums[0] * invn, mu2 = sums[2] * invn;
  float var1 = (float)(sums[1] * invn - mu1 * mu1);
  float var2 = (float)(sums[3] * invn - mu2 * mu2);
  float rs1 = rsqrtf(var1 + 1e-5f), rs2 = rsqrtf(var2 + 1e-5f);
  float a1 = (z1[r] - (float)mu1) * rs1;
  float a2 = (z2[r] - (float)mu2) * rs2;
  a1 = a1 > 0.f ? a1 : 0.01f * a1;
  a2 = a2 > 0.f ? a2 : 0.01f * a2;
  float mx = fmaxf(a1, a2);
  float e1 = __expf(a1 - mx), e2 = __expf(a2 - mx);
  float inv = 1.f / (e1 + e2);
  float out = (e1 * inv) * p[idx] + (e2 * inv) * q[idx]
            + hu_all[(size_t)r * 192 + l * 64 + j];
  hu_all[(size_t)r * 192 + (l + 1) * 64 + j] = out;
}

// ---- final scoring: 4 pairs per wave (16 lanes each), float4 loads ----
__global__ void k_score(const int* __restrict__ pu, const int* __restrict__ pi,
                        const int* __restrict__ nu, const int* __restrict__ ni,
                        const float* __restrict__ hu_all, const float* __restrict__ hi_all,
                        float* __restrict__ out, int EP){
  int gw = blockIdx.x * 4 + (threadIdx.x >> 6);
  int sub = (threadIdx.x >> 4) & 3, l16 = threadIdx.x & 15;
  int k = gw * 4 + sub;
  if (k >= 2 * EP) return;
  int u, i;
  if (k < EP){ u = pu[k]; i = pi[k]; } else { u = nu[k - EP]; i = ni[k - EP]; }
  const float4* hu = (const float4*)(hu_all + (size_t)u * 192);
  const float4* hi = (const float4*)(hi_all + (size_t)i * 192);
  float acc = 0.f;
#pragma unroll
  for (int t = 0; t < 3; ++t){
    float4 a = hu[l16 + 16 * t];
    float4 b = hi[l16 + 16 * t];
    acc += a.x * b.x + a.y * b.y + a.z * b.z + a.w * b.w;
  }
#pragma unroll
  for (int o = 8; o > 0; o >>= 1) acc += __shfl_xor(acc, o, 64);
  if (l16 == 0) out[k] = acc;
}

extern "C" void kernel_launch(void* const* d_in, const int* in_sizes, int n_in,
                              void* d_out, int out_size, void* d_ws, size_t ws_size,
                              hipStream_t stream) {
  const int*   rate_src  = (const int*)  d_in[0];
  const int*   rate_dst  = (const int*)  d_in[1];
  const int*   trust_src = (const int*)  d_in[2];
  const int*   trust_dst = (const int*)  d_in[3];
  const int*   pos_u     = (const int*)  d_in[4];
  const int*   pos_i     = (const int*)  d_in[5];
  const int*   neg_u     = (const int*)  d_in[6];
  const int*   neg_i     = (const int*)  d_in[7];
  const float* eu        = (const float*)d_in[8];
  const float* ei        = (const float*)d_in[9];
  const float* rate_W    = (const float*)d_in[10];
  const float* rate_b    = (const float*)d_in[11];
  const float* rate_attn = (const float*)d_in[12];
  const float* rate_bias = (const float*)d_in[13];
  const float* rb_W      = (const float*)d_in[14];
  const float* rb_b      = (const float*)d_in[15];
  const float* rb_attn   = (const float*)d_in[16];
  const float* rb_bias   = (const float*)d_in[17];
  const float* tr_W      = (const float*)d_in[18];
  const float* tr_b      = (const float*)d_in[19];
  const float* tr_attn   = (const float*)d_in[20];
  const float* tr_bias   = (const float*)d_in[21];
  const float* attW1     = (const float*)d_in[22];
  const float* attb1     = (const float*)d_in[23];
  const float* attW2     = (const float*)d_in[24];
  const float* attb2     = (const float*)d_in[25];

  const int ER = in_sizes[0];
  const int ET = in_sizes[2];
  const int EP = in_sizes[4];
  const int NU = in_sizes[8] / 64;
  const int NI = in_sizes[9] / 64;

  // ---- workspace layout: f32 region then int region ----
  float* ws = (float*)d_ws;
  float*  hu_all = ws;                                   // NU*192
  float*  hi_all = hu_all + (size_t)NU * 192;            // NI*192
  float*  p      = hi_all + (size_t)NI * 192;            // NU*64
  float*  q      = p + (size_t)NU * 64;                  // NU*64
  bf16*   fs     = (bf16*)(q + (size_t)NU * 64);         // NU*64 bf16 (in NU*64 f32 slot)
  bf16*   fd     = (bf16*)(q + (size_t)NU * 128);        // NU*64 bf16
  float*  z1     = q + (size_t)NU * 192;                 // NU
  float*  z2     = z1 + NU;                              // NU
  float*  bsums  = z2 + NU;                              // cdiv(NU,4)*4
  float*  vvec   = bsums + (size_t)(((NU + 3) / 4) * 4); // 512
  float*  cs     = vvec + 512;                           // 4
  double* sums   = (double*)(((uintptr_t)(cs + 4) + 15) & ~(uintptr_t)15); // 4
  double* gpart  = sums + 4;           // 128*4 doubles
  int*    iw     = (int*)(gpart + 512);
  int*    cntA   = iw;                 // NI
  int*    cntB   = cntA + NI;          // NU
  int*    cntC   = cntB + NU;          // NU
  int*    gbase  = cntC + NU;          // 4 (3 used)
  int*    offsA  = gbase + 4;          // NI
  int*    curA   = offsA + NI;         // NI
  int*    offsB  = curA + NI;          // NU
  int*    curB   = offsB + NU;         // NU
  int*    offsC  = curB + NU;          // NU
  int*    curC   = offsC + NU;         // NU
  int*    csrA   = curC + NU;          // ER (user srcs, grouped by item)
  int*    csrB   = csrA + ER;          // ER (item srcs, grouped by user)
  int*    csrC   = csrB + ER;          // ET (user srcs, grouped by dst user)

  auto cdiv = [](int a, int b){ return (a + b - 1) / b; };
  const int nbz = cdiv(NU, 4);

  // ---- one-time per call: init state + gate MLP collapse + CSR builds ----
  k_copy_in<<<cdiv(NU * 64, 256), 256, 0, stream>>>(eu, hu_all, NU, 192);
  k_copy_in<<<cdiv(NI * 64, 256), 256, 0, stream>>>(ei, hi_all, NI, 192);
  k_attvec<<<1, 512, 0, stream>>>(attW1, attb1, attW2, attb2, vvec, cs);

  hipMemsetAsync(cntA, 0, (size_t)(NI + 2 * NU + 4) * 4, stream);
  k_hist2<<<cdiv(ER, 256), 256, 0, stream>>>(rate_src, rate_dst, cntA, cntB, ER);
  k_hist<<<cdiv(ET, 256), 256, 0, stream>>>(trust_dst, cntC, ET);
  k_scan_mb<<<cdiv(NI, 1024), 1024, 0, stream>>>(cntA, NI, offsA, curA, gbase + 0);
  k_scan_mb<<<cdiv(NU, 1024), 1024, 0, stream>>>(cntB, NU, offsB, curB, gbase + 1);
  k_scan_mb<<<cdiv(NU, 1024), 1024, 0, stream>>>(cntC, NU, offsC, curC, gbase + 2);
  k_csr_fill2<<<cdiv(ER, 256), 256, 0, stream>>>(rate_src, rate_dst,
      curA, csrA, curB, csrB, ER);
  k_csr_fill<<<cdiv(ET, 256), 256, 0, stream>>>(trust_src, trust_dst, curC, csrC, ET);

  for (int l = 0; l < 2; ++l){
    // ---------- rate GAT: users -> items, into hi_all block l+1 (+bias+residual) ----------
    k_linear<<<cdiv(NU, 64), 256, 0, stream>>>(hu_all, 192, l * 64,
        rate_W + (size_t)(l * 2 + 0) * 4096, rate_b + (l * 2 + 0) * 64, fs, NU);
    k_linear<<<cdiv(NI, 64), 256, 0, stream>>>(hi_all, 192, l * 64,
        rate_W + (size_t)(l * 2 + 1) * 4096, rate_b + (l * 2 + 1) * 64, fd, NI);
    k_gat<<<cdiv(NI, 4), 256, 0, stream>>>(offsA, cntA, csrA, fs, fd,
        rate_attn + l * 64, rate_bias + l * 64,
        hi_all, 192, (l + 1) * 64, hi_all, 192, l * 64, NI);

    // ---------- rated-by GAT: items -> users, result q ----------
    k_linear<<<cdiv(NI, 64), 256, 0, stream>>>(hi_all, 192, l * 64,
        rb_W + (size_t)(l * 2 + 0) * 4096, rb_b + (l * 2 + 0) * 64, fs, NI);
    k_linear<<<cdiv(NU, 64), 256, 0, stream>>>(hu_all, 192, l * 64,
        rb_W + (size_t)(l * 2 + 1) * 4096, rb_b + (l * 2 + 1) * 64, fd, NU);
    k_gat<<<cdiv(NU, 4), 256, 0, stream>>>(offsB, cntB, csrB, fs, fd,
        rb_attn + l * 64, rb_bias + l * 64,
        q, 64, 0, (const float*)nullptr, 0, 0, NU);

    // ---------- trust GAT: users -> users, result p ----------
    k_linear<<<cdiv(NU, 64), 256, 0, stream>>>(hu_all, 192, l * 64,
        tr_W + (size_t)(l * 2 + 0) * 4096, tr_b + (l * 2 + 0) * 64, fs, NU);
    k_linear<<<cdiv(NU, 64), 256, 0, stream>>>(hu_all, 192, l * 64,
        tr_W + (size_t)(l * 2 + 1) * 4096, tr_b + (l * 2 + 1) * 64, fd, NU);
    k_gat<<<cdiv(NU, 4), 256, 0, stream>>>(offsC, cntC, csrC, fs, fd,
        tr_attn + l * 64, tr_bias + l * 64,
        p, 64, 0, (const float*)nullptr, 0, 0, NU);

    // ---------- attention gate + combine -> hu_all block l+1 ----------
    k_gate_z<<<nbz, 256, 0, stream>>>(hu_all, l, p, q, vvec, cs, z1, z2, bsums, NU);
    k_bn_part<<<128, 256, 0, stream>>>(bsums, nbz, gpart);
    k_bn_final<<<1, 256, 0, stream>>>(gpart, 128, sums);
    k_gate_combine<<<cdiv(NU * 64, 256), 256, 0, stream>>>(hu_all, l, p, q, z1, z2, sums, NU);
  }

  // ---------- final scoring ----------
  k_score<<<cdiv(2 * EP, 16), 256, 0, stream>>>(pos_u, pos_i, neg_u, neg_i,
      hu_all, hi_all, (float*)d_out, EP);
}

// Round 10
// 1070.220 us; speedup vs baseline: 1.7740x; 1.1840x over previous
//
#include <hip/hip_runtime.h>
#include <hip/hip_bf16.h>
#include <cstdint>

typedef __hip_bfloat16 bf16;
typedef __attribute__((ext_vector_type(8))) short frag_ab;   // 8 bf16 (4 VGPRs)
typedef __attribute__((ext_vector_type(4))) float frag_cd;   // 4 fp32
typedef __attribute__((ext_vector_type(4))) short short4v;   // 4 bf16 bits

__device__ __forceinline__ float b2f(short s){
  return __uint_as_float(((unsigned)(unsigned short)s) << 16);
}

// split f32 into hi/lo bf16 bit patterns (x ~= hi + lo, rel err ~2^-17)
__device__ __forceinline__ void bf_split(float x, short& hi, short& lo){
  bf16 h = __float2bfloat16(x);
  float hf = __bfloat162float(h);
  bf16 l = __float2bfloat16(x - hf);
  __builtin_memcpy(&hi, &h, 2);
  __builtin_memcpy(&lo, &l, 2);
}

__device__ __forceinline__ float wave_sum(float v){
#pragma unroll
  for (int o = 32; o > 0; o >>= 1) v += __shfl_down(v, o, 64);
  return v;  // lane 0 holds the sum
}

// ---- copy f32 [n,64] -> f32 strided [n, stride] ----
__global__ void k_copy_in(const float* __restrict__ src, float* __restrict__ dst,
                          int n, int stride){
  int idx = blockIdx.x * 256 + threadIdx.x;
  if (idx >= n * 64) return;
  int r = idx >> 6, j = idx & 63;
  dst[(size_t)r * stride + j] = src[idx];
}

// ---- out_bf[n,64] = bf16( x[n, xo:xo+64] @ W(64x64) + b )  via split-bf16 MFMA ----
__global__ void k_linear(const float* __restrict__ x, int xs, int xo,
                         const float* __restrict__ W, const float* __restrict__ b,
                         bf16* __restrict__ out, int n){
  __shared__ float Wl[4096];
  int t = threadIdx.x;
  for (int i = t; i < 4096; i += 256) Wl[i] = W[i];
  __syncthreads();
  int lane = t & 63, w = t >> 6;
  int quad = lane >> 4, n16 = lane & 15;

  frag_ab bhi[4][2], blo[4][2];
#pragma unroll
  for (int c = 0; c < 4; ++c)
#pragma unroll
    for (int h = 0; h < 2; ++h){
      frag_ab vh, vl;
#pragma unroll
      for (int j = 0; j < 8; ++j){
        float wv = Wl[(32 * h + quad * 8 + j) * 64 + 16 * c + n16];
        short sh, sl; bf_split(wv, sh, sl);
        vh[j] = sh; vl[j] = sl;
      }
      bhi[c][h] = vh; blo[c][h] = vl;
    }
  float bj[4];
#pragma unroll
  for (int c = 0; c < 4; ++c) bj[c] = b[16 * c + n16];

  int rowbase = blockIdx.x * 64 + w * 16;
  if (rowbase >= n) return;
  int lrow = rowbase + n16; if (lrow >= n) lrow = n - 1;   // clamp (stores guarded)
  const float* xp = x + (size_t)lrow * xs + xo;
  frag_ab ahi[2], alo[2];
#pragma unroll
  for (int h = 0; h < 2; ++h){
    frag_ab vh, vl;
#pragma unroll
    for (int j = 0; j < 8; ++j){
      float xv = xp[32 * h + quad * 8 + j];
      short sh, sl; bf_split(xv, sh, sl);
      vh[j] = sh; vl[j] = sl;
    }
    ahi[h] = vh; alo[h] = vl;
  }
  frag_cd acc[4];
#pragma unroll
  for (int c = 0; c < 4; ++c) acc[c] = frag_cd{0.f, 0.f, 0.f, 0.f};
#pragma unroll
  for (int c = 0; c < 4; ++c)
#pragma unroll
    for (int h = 0; h < 2; ++h){
      acc[c] = __builtin_amdgcn_mfma_f32_16x16x32_bf16(ahi[h], bhi[c][h], acc[c], 0, 0, 0);
      acc[c] = __builtin_amdgcn_mfma_f32_16x16x32_bf16(alo[h], bhi[c][h], acc[c], 0, 0, 0);
      acc[c] = __builtin_amdgcn_mfma_f32_16x16x32_bf16(ahi[h], blo[c][h], acc[c], 0, 0, 0);
    }
#pragma unroll
  for (int reg = 0; reg < 4; ++reg){
    int r = rowbase + quad * 4 + reg;
    if (r >= n) continue;
#pragma unroll
    for (int c = 0; c < 4; ++c)
      out[(size_t)r * 64 + 16 * c + n16] = __float2bfloat16(acc[c][reg] + bj[c]);
  }
}

// ================= CSR build (per call; ws is re-poisoned) =================
__global__ void k_hist(const int* __restrict__ dst, int* __restrict__ cnt, int E){
  int k = blockIdx.x * 256 + threadIdx.x;
  if (k < E) atomicAdd(cnt + dst[k], 1);
}
__global__ void k_hist2(const int* __restrict__ src, const int* __restrict__ dst,
                        int* __restrict__ cntA, int* __restrict__ cntB, int E){
  int k = blockIdx.x * 256 + threadIdx.x;
  if (k >= E) return;
  atomicAdd(cntA + dst[k], 1);
  atomicAdd(cntB + src[k], 1);
}

// multi-block scan: block grabs contiguous range via atomicAdd on gbase.
__global__ void k_scan_mb(const int* __restrict__ cnt, int n,
                          int* __restrict__ offs, int* __restrict__ cur,
                          int* __restrict__ gbase){
  __shared__ int wsum[16];
  __shared__ int base_sh;
  int t = threadIdx.x, lane = t & 63, w = t >> 6;
  int i = blockIdx.x * 1024 + t;
  int v = (i < n) ? cnt[i] : 0;
  int x = v;
#pragma unroll
  for (int o = 1; o < 64; o <<= 1){
    int y = __shfl_up(x, o, 64);
    if (lane >= o) x += y;
  }
  if (lane == 63) wsum[w] = x;
  __syncthreads();
  if (t == 0){
    int tot = 0;
    for (int k = 0; k < 16; ++k){ int c = wsum[k]; wsum[k] = tot; tot += c; }
    base_sh = atomicAdd(gbase, tot);
  }
  __syncthreads();
  if (i < n){
    int e = base_sh + wsum[w] + x - v;
    offs[i] = e; cur[i] = e;
  }
}

// batched fills: 4 edges per thread, all atomics issued before stores (MLP=8/4)
__global__ void k_csr_fill(const int* __restrict__ src, const int* __restrict__ dst,
                           int* __restrict__ cur, int* __restrict__ csr_src, int E){
  int t = blockIdx.x * 256 + threadIdx.x;
  int T = gridDim.x * 256;
  int k0 = t, k1 = t + T, k2 = t + 2 * T, k3 = t + 3 * T;
  bool b0 = k0 < E, b1 = k1 < E, b2 = k2 < E, b3 = k3 < E;
  int s0 = 0, d0 = 0, s1 = 0, d1 = 0, s2 = 0, d2 = 0, s3 = 0, d3 = 0;
  if (b0){ s0 = src[k0]; d0 = dst[k0]; }
  if (b1){ s1 = src[k1]; d1 = dst[k1]; }
  if (b2){ s2 = src[k2]; d2 = dst[k2]; }
  if (b3){ s3 = src[k3]; d3 = dst[k3]; }
  int p0 = 0, p1 = 0, p2 = 0, p3 = 0;
  if (b0) p0 = atomicAdd(cur + d0, 1);
  if (b1) p1 = atomicAdd(cur + d1, 1);
  if (b2) p2 = atomicAdd(cur + d2, 1);
  if (b3) p3 = atomicAdd(cur + d3, 1);
  if (b0) csr_src[p0] = s0;
  if (b1) csr_src[p1] = s1;
  if (b2) csr_src[p2] = s2;
  if (b3) csr_src[p3] = s3;
}
__global__ void k_csr_fill2(const int* __restrict__ src, const int* __restrict__ dst,
                            int* __restrict__ curA, int* __restrict__ csrA,
                            int* __restrict__ curB, int* __restrict__ csrB, int E){
  int t = blockIdx.x * 256 + threadIdx.x;
  int T = gridDim.x * 256;
  int k0 = t, k1 = t + T, k2 = t + 2 * T, k3 = t + 3 * T;
  bool b0 = k0 < E, b1 = k1 < E, b2 = k2 < E, b3 = k3 < E;
  int s0 = 0, d0 = 0, s1 = 0, d1 = 0, s2 = 0, d2 = 0, s3 = 0, d3 = 0;
  if (b0){ s0 = src[k0]; d0 = dst[k0]; }
  if (b1){ s1 = src[k1]; d1 = dst[k1]; }
  if (b2){ s2 = src[k2]; d2 = dst[k2]; }
  if (b3){ s3 = src[k3]; d3 = dst[k3]; }
  int pa0 = 0, pa1 = 0, pa2 = 0, pa3 = 0, pb0 = 0, pb1 = 0, pb2 = 0, pb3 = 0;
  if (b0) pa0 = atomicAdd(curA + d0, 1);
  if (b1) pa1 = atomicAdd(curA + d1, 1);
  if (b2) pa2 = atomicAdd(curA + d2, 1);
  if (b3) pa3 = atomicAdd(curA + d3, 1);
  if (b0) pb0 = atomicAdd(curB + s0, 1);
  if (b1) pb1 = atomicAdd(curB + s1, 1);
  if (b2) pb2 = atomicAdd(curB + s2, 1);
  if (b3) pb3 = atomicAdd(curB + s3, 1);
  if (b0){ csrA[pa0] = s0; csrB[pb0] = d0; }
  if (b1){ csrA[pa1] = s1; csrB[pb1] = d1; }
  if (b2){ csrA[pa2] = s2; csrB[pb2] = d2; }
  if (b3){ csrA[pa3] = s3; csrB[pb3] = d3; }
}

// ============ fused GATv2 aggregation: 16 lanes/edge, 4 edges per wave ============
// lane handles 4 features (bf16x4, 8B load -> one VMEM inst covers 4 rows/wave);
// 4-shfl in-group reduce + 1 expf per lane per 4 edges (vs 24 shfl + 4 expf before).
__global__ void k_gat(const int* __restrict__ offs, const int* __restrict__ cnt,
                      const int* __restrict__ csr_src,
                      const bf16* __restrict__ fs, const bf16* __restrict__ fd,
                      const float* __restrict__ attn, const float* __restrict__ bias,
                      float* __restrict__ out, int os, int oo,
                      const float* __restrict__ res, int rs, int ro, int n){
  int d = blockIdx.x * 4 + (threadIdx.x >> 6);
  if (d >= n) return;
  int lane = threadIdx.x & 63;
  int g = lane >> 4, l16 = lane & 15;
  short4v dv = *(const short4v*)(fd + (size_t)d * 64 + 4 * l16);
  float fd0 = b2f(dv[0]), fd1 = b2f(dv[1]), fd2 = b2f(dv[2]), fd3 = b2f(dv[3]);
  float4 a4 = *(const float4*)(attn + 4 * l16);
  float acc0 = 0.f, acc1 = 0.f, acc2 = 0.f, acc3 = 0.f, den = 0.f;
  int idx0 = offs[d], end = idx0 + cnt[d];
  for (int idx = idx0; idx < end; idx += 4){
    int e = idx + g;
    bool valid = e < end;
    int s = csr_src[valid ? e : idx];
    short4v sv = *(const short4v*)(fs + (size_t)s * 64 + 4 * l16);
    float f0 = b2f(sv[0]), f1 = b2f(sv[1]), f2 = b2f(sv[2]), f3 = b2f(sv[3]);
    float v0 = f0 + fd0; v0 = (v0 > 0.f ? v0 : 0.2f * v0) * a4.x;
    float v1 = f1 + fd1; v1 = (v1 > 0.f ? v1 : 0.2f * v1) * a4.y;
    float v2 = f2 + fd2; v2 = (v2 > 0.f ? v2 : 0.2f * v2) * a4.z;
    float v3 = f3 + fd3; v3 = (v3 > 0.f ? v3 : 0.2f * v3) * a4.w;
    float tt = (v0 + v1) + (v2 + v3);
#pragma unroll
    for (int o = 1; o < 16; o <<= 1) tt += __shfl_xor(tt, o, 64);  // in-group (16)
    float ex = valid ? __expf(tt) : 0.f;
    acc0 += ex * f0; acc1 += ex * f1; acc2 += ex * f2; acc3 += ex * f3;
    den += ex;
  }
  // cross-group reduce (groups differ only in g: offsets 16, 32)
#pragma unroll
  for (int o = 16; o < 64; o <<= 1){
    acc0 += __shfl_xor(acc0, o, 64); acc1 += __shfl_xor(acc1, o, 64);
    acc2 += __shfl_xor(acc2, o, 64); acc3 += __shfl_xor(acc3, o, 64);
    den  += __shfl_xor(den, o, 64);
  }
  if (g == 0){
    float4 b4 = *(const float4*)(bias + 4 * l16);
    float inv = (den > 0.f) ? 1.f / den : 0.f;   // empty segment -> bias only
    float o0 = acc0 * inv + b4.x, o1 = acc1 * inv + b4.y;
    float o2 = acc2 * inv + b4.z, o3 = acc3 * inv + b4.w;
    if (res){
      float4 r4 = *(const float4*)(res + (size_t)d * rs + ro + 4 * l16);
      o0 += r4.x; o1 += r4.y; o2 += r4.z; o3 += r4.w;
    }
    *(float4*)(out + (size_t)d * os + oo + 4 * l16) = make_float4(o0, o1, o2, o3);
  }
}

// ---- collapse attention-gate MLP: v = W1@W2 (per l,i), c = b1@W2 + b2 ----
__global__ void k_attvec(const float* __restrict__ W1, const float* __restrict__ b1,
                         const float* __restrict__ W2, const float* __restrict__ b2,
                         float* __restrict__ vvec, float* __restrict__ cs){
  int t = threadIdx.x;
  int li = t >> 7, r = t & 127;
  float acc = 0.f;
  for (int c = 0; c < 128; ++c)
    acc += W1[(size_t)(li * 128 + r) * 128 + c] * W2[li * 128 + c];
  vvec[li * 128 + r] = acc;
  if (r == 0){
    float cacc = b2[li];
    for (int c = 0; c < 128; ++c)
      cacc += b1[li * 128 + c] * W2[li * 128 + c];
    cs[li] = cacc;
  }
}

// ---- gate z-scores + per-block partial sums for BatchNorm ----
__global__ void k_gate_z(const float* __restrict__ hu_all, int l,
                         const float* __restrict__ p, const float* __restrict__ q,
                         const float* __restrict__ vvec, const float* __restrict__ cs,
                         float* __restrict__ z1, float* __restrict__ z2,
                         float* __restrict__ bsums, int n){
  __shared__ float part[4][4];
  int w = threadIdx.x >> 6, j = threadIdx.x & 63;
  int nidx = blockIdx.x * 4 + w;
  float lz1 = 0.f, lz2 = 0.f;
  if (nidx < n){
    const float* v1 = vvec + l * 256;
    const float* v2 = vvec + l * 256 + 128;
    float h  = hu_all[(size_t)nidx * 192 + l * 64 + j];
    float pv = p[(size_t)nidx * 64 + j];
    float qv = q[(size_t)nidx * 64 + j];
    float t1 = wave_sum(h * v1[j] + pv * v1[64 + j]);
    float t2 = wave_sum(h * v2[j] + qv * v2[64 + j]);
    if (j == 0){
      lz1 = t1 + cs[l * 2 + 0];
      lz2 = t2 + cs[l * 2 + 1];
      z1[nidx] = lz1;
      z2[nidx] = lz2;
    }
  }
  if (j == 0){
    part[w][0] = lz1; part[w][1] = lz1 * lz1;
    part[w][2] = lz2; part[w][3] = lz2 * lz2;
  }
  __syncthreads();
  if (threadIdx.x < 4)
    bsums[(size_t)blockIdx.x * 4 + threadIdx.x] =
        part[0][threadIdx.x] + part[1][threadIdx.x] +
        part[2][threadIdx.x] + part[3][threadIdx.x];
}

// ---- BN reduce stage 1: 128 blocks grid-stride -> gpart[128][4] ----
__global__ void k_bn_part(const float* __restrict__ bsums, int nb,
                          double* __restrict__ gpart){
  __shared__ double sh[256];
  int c = threadIdx.x & 3, r0 = blockIdx.x * 64 + (threadIdx.x >> 2);
  double acc = 0.0;
  for (int i = r0; i < nb; i += gridDim.x * 64)
    acc += (double)bsums[(size_t)i * 4 + c];
  sh[threadIdx.x] = acc;
  __syncthreads();
  for (int s = 128; s >= 4; s >>= 1){
    if (threadIdx.x < s) sh[threadIdx.x] += sh[threadIdx.x + s];
    __syncthreads();
  }
  if (threadIdx.x < 4) gpart[(size_t)blockIdx.x * 4 + threadIdx.x] = sh[threadIdx.x];
}

// ---- BN reduce stage 2: single block over 128 partials -> sums[4] ----
__global__ void k_bn_final(const double* __restrict__ gpart, int nbk,
                           double* __restrict__ sums){
  __shared__ double sh[256];
  int c = threadIdx.x & 3, k0 = threadIdx.x >> 2;
  double acc = 0.0;
  for (int i = k0; i < nbk; i += 64) acc += gpart[(size_t)i * 4 + c];
  sh[threadIdx.x] = acc;
  __syncthreads();
  for (int s = 128; s >= 4; s >>= 1){
    if (threadIdx.x < s) sh[threadIdx.x] += sh[threadIdx.x + s];
    __syncthreads();
  }
  if (threadIdx.x < 4) sums[threadIdx.x] = sh[threadIdx.x];
}

// ---- BN + lrelu(0.01) + softmax gate + residual combine ----
__global__ void k_gate_combine(float* __restrict__ hu_all, int l,
                               const float* __restrict__ p, const float* __restrict__ q,
                               const float* __restrict__ z1, const float* __restrict__ z2,
                               const double* __restrict__ sums, int n){
  int idx = blockIdx.x * 256 + threadIdx.x;
  if (idx >= n * 64) return;
  int r = idx >> 6, j = idx & 63;
  double invn = 1.0 / (double)n;
  double mu1 = sums[0] * invn, mu2 = sums[2] * invn;
  float var1 = (float)(sums[1] * invn - mu1 * mu1);
  float var2 = (float)(sums[3] * invn - mu2 * mu2);
  float rs1 = rsqrtf(var1 + 1e-5f), rs2 = rsqrtf(var2 + 1e-5f);
  float a1 = (z1[r] - (float)mu1) * rs1;
  float a2 = (z2[r] - (float)mu2) * rs2;
  a1 = a1 > 0.f ? a1 : 0.01f * a1;
  a2 = a2 > 0.f ? a2 : 0.01f * a2;
  float mx = fmaxf(a1, a2);
  float e1 = __expf(a1 - mx), e2 = __expf(a2 - mx);
  float inv = 1.f / (e1 + e2);
  float out = (e1 * inv) * p[idx] + (e2 * inv) * q[idx]
            + hu_all[(size_t)r * 192 + l * 64 + j];
  hu_all[(size_t)r * 192 + (l + 1) * 64 + j] = out;
}

// ---- final scoring: 4 pairs per wave (16 lanes each), float4 loads ----
__global__ void k_score(const int* __restrict__ pu, const int* __restrict__ pi,
                        const int* __restrict__ nu, const int* __restrict__ ni,
                        const float* __restrict__ hu_all, const float* __restrict__ hi_all,
                        float* __restrict__ out, int EP){
  int gw = blockIdx.x * 4 + (threadIdx.x >> 6);
  int sub = (threadIdx.x >> 4) & 3, l16 = threadIdx.x & 15;
  int k = gw * 4 + sub;
  if (k >= 2 * EP) return;
  int u, i;
  if (k < EP){ u = pu[k]; i = pi[k]; } else { u = nu[k - EP]; i = ni[k - EP]; }
  const float4* hu = (const float4*)(hu_all + (size_t)u * 192);
  const float4* hi = (const float4*)(hi_all + (size_t)i * 192);
  float acc = 0.f;
#pragma unroll
  for (int t = 0; t < 3; ++t){
    float4 a = hu[l16 + 16 * t];
    float4 b = hi[l16 + 16 * t];
    acc += a.x * b.x + a.y * b.y + a.z * b.z + a.w * b.w;
  }
#pragma unroll
  for (int o = 8; o > 0; o >>= 1) acc += __shfl_xor(acc, o, 64);
  if (l16 == 0) out[k] = acc;
}

extern "C" void kernel_launch(void* const* d_in, const int* in_sizes, int n_in,
                              void* d_out, int out_size, void* d_ws, size_t ws_size,
                              hipStream_t stream) {
  const int*   rate_src  = (const int*)  d_in[0];
  const int*   rate_dst  = (const int*)  d_in[1];
  const int*   trust_src = (const int*)  d_in[2];
  const int*   trust_dst = (const int*)  d_in[3];
  const int*   pos_u     = (const int*)  d_in[4];
  const int*   pos_i     = (const int*)  d_in[5];
  const int*   neg_u     = (const int*)  d_in[6];
  const int*   neg_i     = (const int*)  d_in[7];
  const float* eu        = (const float*)d_in[8];
  const float* ei        = (const float*)d_in[9];
  const float* rate_W    = (const float*)d_in[10];
  const float* rate_b    = (const float*)d_in[11];
  const float* rate_attn = (const float*)d_in[12];
  const float* rate_bias = (const float*)d_in[13];
  const float* rb_W      = (const float*)d_in[14];
  const float* rb_b      = (const float*)d_in[15];
  const float* rb_attn   = (const float*)d_in[16];
  const float* rb_bias   = (const float*)d_in[17];
  const float* tr_W      = (const float*)d_in[18];
  const float* tr_b      = (const float*)d_in[19];
  const float* tr_attn   = (const float*)d_in[20];
  const float* tr_bias   = (const float*)d_in[21];
  const float* attW1     = (const float*)d_in[22];
  const float* attb1     = (const float*)d_in[23];
  const float* attW2     = (const float*)d_in[24];
  const float* attb2     = (const float*)d_in[25];

  const int ER = in_sizes[0];
  const int ET = in_sizes[2];
  const int EP = in_sizes[4];
  const int NU = in_sizes[8] / 64;
  const int NI = in_sizes[9] / 64;

  // ---- workspace layout: f32 region then int region ----
  float* ws = (float*)d_ws;
  float*  hu_all = ws;                                   // NU*192
  float*  hi_all = hu_all + (size_t)NU * 192;            // NI*192
  float*  p      = hi_all + (size_t)NI * 192;            // NU*64
  float*  q      = p + (size_t)NU * 64;                  // NU*64
  bf16*   fs     = (bf16*)(q + (size_t)NU * 64);         // NU*64 bf16
  bf16*   fd     = (bf16*)(q + (size_t)NU * 128);        // NU*64 bf16
  float*  z1     = q + (size_t)NU * 192;                 // NU
  float*  z2     = z1 + NU;                              // NU
  float*  bsums  = z2 + NU;                              // cdiv(NU,4)*4
  float*  vvec   = bsums + (size_t)(((NU + 3) / 4) * 4); // 512
  float*  cs     = vvec + 512;                           // 4
  double* sums   = (double*)(((uintptr_t)(cs + 4) + 15) & ~(uintptr_t)15); // 4
  double* gpart  = sums + 4;           // 128*4 doubles
  int*    iw     = (int*)(gpart + 512);
  int*    cntA   = iw;                 // NI
  int*    cntB   = cntA + NI;          // NU
  int*    cntC   = cntB + NU;          // NU
  int*    gbase  = cntC + NU;          // 4 (3 used)
  int*    offsA  = gbase + 4;          // NI
  int*    curA   = offsA + NI;         // NI
  int*    offsB  = curA + NI;          // NU
  int*    curB   = offsB + NU;         // NU
  int*    offsC  = curB + NU;          // NU
  int*    curC   = offsC + NU;         // NU
  int*    csrA   = curC + NU;          // ER (user srcs, grouped by item)
  int*    csrB   = csrA + ER;          // ER (item srcs, grouped by user)
  int*    csrC   = csrB + ER;          // ET (user srcs, grouped by dst user)

  auto cdiv = [](int a, int b){ return (a + b - 1) / b; };
  const int nbz = cdiv(NU, 4);

  // ---- one-time per call: init state + gate MLP collapse + CSR builds ----
  k_copy_in<<<cdiv(NU * 64, 256), 256, 0, stream>>>(eu, hu_all, NU, 192);
  k_copy_in<<<cdiv(NI * 64, 256), 256, 0, stream>>>(ei, hi_all, NI, 192);
  k_attvec<<<1, 512, 0, stream>>>(attW1, attb1, attW2, attb2, vvec, cs);

  hipMemsetAsync(cntA, 0, (size_t)(NI + 2 * NU + 4) * 4, stream);
  k_hist2<<<cdiv(ER, 256), 256, 0, stream>>>(rate_src, rate_dst, cntA, cntB, ER);
  k_hist<<<cdiv(ET, 256), 256, 0, stream>>>(trust_dst, cntC, ET);
  k_scan_mb<<<cdiv(NI, 1024), 1024, 0, stream>>>(cntA, NI, offsA, curA, gbase + 0);
  k_scan_mb<<<cdiv(NU, 1024), 1024, 0, stream>>>(cntB, NU, offsB, curB, gbase + 1);
  k_scan_mb<<<cdiv(NU, 1024), 1024, 0, stream>>>(cntC, NU, offsC, curC, gbase + 2);
  k_csr_fill2<<<cdiv(ER, 1024), 256, 0, stream>>>(rate_src, rate_dst,
      curA, csrA, curB, csrB, ER);
  k_csr_fill<<<cdiv(ET, 1024), 256, 0, stream>>>(trust_src, trust_dst, curC, csrC, ET);

  for (int l = 0; l < 2; ++l){
    // ---------- rate GAT: users -> items, into hi_all block l+1 (+bias+residual) ----------
    k_linear<<<cdiv(NU, 64), 256, 0, stream>>>(hu_all, 192, l * 64,
        rate_W + (size_t)(l * 2 + 0) * 4096, rate_b + (l * 2 + 0) * 64, fs, NU);
    k_linear<<<cdiv(NI, 64), 256, 0, stream>>>(hi_all, 192, l * 64,
        rate_W + (size_t)(l * 2 + 1) * 4096, rate_b + (l * 2 + 1) * 64, fd, NI);
    k_gat<<<cdiv(NI, 4), 256, 0, stream>>>(offsA, cntA, csrA, fs, fd,
        rate_attn + l * 64, rate_bias + l * 64,
        hi_all, 192, (l + 1) * 64, hi_all, 192, l * 64, NI);

    // ---------- rated-by GAT: items -> users, result q ----------
    k_linear<<<cdiv(NI, 64), 256, 0, stream>>>(hi_all, 192, l * 64,
        rb_W + (size_t)(l * 2 + 0) * 4096, rb_b + (l * 2 + 0) * 64, fs, NI);
    k_linear<<<cdiv(NU, 64), 256, 0, stream>>>(hu_all, 192, l * 64,
        rb_W + (size_t)(l * 2 + 1) * 4096, rb_b + (l * 2 + 1) * 64, fd, NU);
    k_gat<<<cdiv(NU, 4), 256, 0, stream>>>(offsB, cntB, csrB, fs, fd,
        rb_attn + l * 64, rb_bias + l * 64,
        q, 64, 0, (const float*)nullptr, 0, 0, NU);

    // ---------- trust GAT: users -> users, result p ----------
    k_linear<<<cdiv(NU, 64), 256, 0, stream>>>(hu_all, 192, l * 64,
        tr_W + (size_t)(l * 2 + 0) * 4096, tr_b + (l * 2 + 0) * 64, fs, NU);
    k_linear<<<cdiv(NU, 64), 256, 0, stream>>>(hu_all, 192, l * 64,
        tr_W + (size_t)(l * 2 + 1) * 4096, tr_b + (l * 2 + 1) * 64, fd, NU);
    k_gat<<<cdiv(NU, 4), 256, 0, stream>>>(offsC, cntC, csrC, fs, fd,
        tr_attn + l * 64, tr_bias + l * 64,
        p, 64, 0, (const float*)nullptr, 0, 0, NU);

    // ---------- attention gate + combine -> hu_all block l+1 ----------
    k_gate_z<<<nbz, 256, 0, stream>>>(hu_all, l, p, q, vvec, cs, z1, z2, bsums, NU);
    k_bn_part<<<128, 256, 0, stream>>>(bsums, nbz, gpart);
    k_bn_final<<<1, 256, 0, stream>>>(gpart, 128, sums);
    k_gate_combine<<<cdiv(NU * 64, 256), 256, 0, stream>>>(hu_all, l, p, q, z1, z2, sums, NU);
  }

  // ---------- final scoring ----------
  k_score<<<cdiv(2 * EP, 16), 256, 0, stream>>>(pos_u, pos_i, neg_u, neg_i,
      hu_all, hi_all, (float*)d_out, EP);
}

// Round 11
// 1008.732 us; speedup vs baseline: 1.8822x; 1.0610x over previous
//
#include <hip/hip_runtime.h>
#include <hip/hip_bf16.h>
#include <cstdint>

typedef __hip_bfloat16 bf16;
typedef __attribute__((ext_vector_type(8))) short frag_ab;   // 8 bf16 (4 VGPRs)
typedef __attribute__((ext_vector_type(4))) float frag_cd;   // 4 fp32
typedef __attribute__((ext_vector_type(4))) short short4v;   // 4 bf16 bits

__device__ __forceinline__ float b2f(short s){
  return __uint_as_float(((unsigned)(unsigned short)s) << 16);
}
__device__ __forceinline__ void bf_split(float x, short& hi, short& lo){
  bf16 h = __float2bfloat16(x);
  float hf = __bfloat162float(h);
  bf16 l = __float2bfloat16(x - hf);
  __builtin_memcpy(&hi, &h, 2);
  __builtin_memcpy(&lo, &l, 2);
}

__device__ __forceinline__ float wave_sum(float v){
#pragma unroll
  for (int o = 32; o > 0; o >>= 1) v += __shfl_down(v, o, 64);
  return v;
}

// ---- copy f32 [n,64] -> f32 strided [n, stride] ----
__global__ void k_copy_in(const float* __restrict__ src, float* __restrict__ dst,
                          int n, int stride){
  int idx = blockIdx.x * 256 + threadIdx.x;
  if (idx >= n * 64) return;
  int r = idx >> 6, j = idx & 63;
  dst[(size_t)r * stride + j] = src[idx];
}

// ---- pre-split all 12 W matrices into MFMA-fragment-ordered bf16 hi/lo ----
// m = rel*4 + l*2 + io. Dest entry (m, lane, pair=c*2+h, j) at m*4096 + lane*64 + pair*8 + j.
__global__ void k_wsplit(const float* __restrict__ rateW, const float* __restrict__ rbW,
                         const float* __restrict__ trW,
                         short* __restrict__ Whi, short* __restrict__ Wlo){
  int tid = blockIdx.x * 256 + threadIdx.x;       // 12*4096 total
  if (tid >= 12 * 4096) return;
  int m = tid >> 12, rem = tid & 4095;
  int lane = rem >> 6, rem2 = rem & 63;
  int pair = rem2 >> 3, j = rem2 & 7;
  int c = pair >> 1, h = pair & 1;
  int rel = m >> 2, li = m & 3;                    // li = l*2+io
  const float* base = (rel == 0) ? rateW : (rel == 1) ? rbW : trW;
  float v = base[(size_t)li * 4096 + (32 * h + (lane >> 4) * 8 + j) * 64 + 16 * c + (lane & 15)];
  short sh, sl; bf_split(v, sh, sl);
  Whi[tid] = sh; Wlo[tid] = sl;
}

// ---- fused multi-output linear: out_i = bf16(x @ W_i + b_i), i<mcount ----
// W frags pre-split in Whi/Wlo (no LDS, no per-block split). 4 waves/block, 64 rows/block.
__global__ void k_linear_multi(const float* __restrict__ x, int xs, int xo, int n,
                               const short* __restrict__ Whi, const short* __restrict__ Wlo,
                               int mcount,
                               int m0, const float* __restrict__ b0, bf16* __restrict__ o0,
                               int m1, const float* __restrict__ b1, bf16* __restrict__ o1,
                               int m2, const float* __restrict__ b2, bf16* __restrict__ o2,
                               int m3, const float* __restrict__ b3, bf16* __restrict__ o3){
  int lane = threadIdx.x & 63, w = threadIdx.x >> 6;
  int quad = lane >> 4, n16 = lane & 15;
  int rowbase = blockIdx.x * 64 + w * 16;
  if (rowbase >= n) return;
  int lrow = rowbase + n16; if (lrow >= n) lrow = n - 1;   // clamp (stores guarded)
  const float* xp = x + (size_t)lrow * xs + xo;
  frag_ab ahi[2], alo[2];
#pragma unroll
  for (int h = 0; h < 2; ++h){
    frag_ab vh, vl;
#pragma unroll
    for (int j = 0; j < 8; ++j){
      float xv = xp[32 * h + quad * 8 + j];
      short sh, sl; bf_split(xv, sh, sl);
      vh[j] = sh; vl[j] = sl;
    }
    ahi[h] = vh; alo[h] = vl;
  }
  int ms[4] = {m0, m1, m2, m3};
  const float* bs[4] = {b0, b1, b2, b3};
  bf16* os[4] = {o0, o1, o2, o3};
  for (int i = 0; i < mcount; ++i){
    const frag_ab* Bh = (const frag_ab*)(Whi + (size_t)ms[i] * 4096 + lane * 64);
    const frag_ab* Bl = (const frag_ab*)(Wlo + (size_t)ms[i] * 4096 + lane * 64);
    frag_cd acc[4];
#pragma unroll
    for (int c = 0; c < 4; ++c) acc[c] = frag_cd{0.f, 0.f, 0.f, 0.f};
#pragma unroll
    for (int c = 0; c < 4; ++c)
#pragma unroll
      for (int h = 0; h < 2; ++h){
        frag_ab bh = Bh[c * 2 + h], bl = Bl[c * 2 + h];
        acc[c] = __builtin_amdgcn_mfma_f32_16x16x32_bf16(ahi[h], bh, acc[c], 0, 0, 0);
        acc[c] = __builtin_amdgcn_mfma_f32_16x16x32_bf16(alo[h], bh, acc[c], 0, 0, 0);
        acc[c] = __builtin_amdgcn_mfma_f32_16x16x32_bf16(ahi[h], bl, acc[c], 0, 0, 0);
      }
    const float* bb = bs[i];
    bf16* oo = os[i];
#pragma unroll
    for (int reg = 0; reg < 4; ++reg){
      int r = rowbase + quad * 4 + reg;
      if (r >= n) continue;
#pragma unroll
      for (int c = 0; c < 4; ++c)
        oo[(size_t)r * 64 + 16 * c + n16] = __float2bfloat16(acc[c][reg] + bb[16 * c + n16]);
    }
  }
}

// ================= CSR build: hist records per-edge position =================
__global__ void k_hist2pos(const int* __restrict__ src, const int* __restrict__ dst,
                           int* __restrict__ cntA, int* __restrict__ cntB,
                           int* __restrict__ posA, int* __restrict__ posB, int E){
  int k = blockIdx.x * 256 + threadIdx.x;
  if (k >= E) return;
  posA[k] = atomicAdd(cntA + dst[k], 1);
  posB[k] = atomicAdd(cntB + src[k], 1);
}
__global__ void k_histpos(const int* __restrict__ dst, int* __restrict__ cnt,
                          int* __restrict__ pos, int E){
  int k = blockIdx.x * 256 + threadIdx.x;
  if (k >= E) return;
  pos[k] = atomicAdd(cnt + dst[k], 1);
}

// multi-block scan: block grabs contiguous range via atomicAdd on gbase.
// Offsets disjoint but not globally monotone -> consumers use cnt[] for ends.
__global__ void k_scan_mb(const int* __restrict__ cnt, int n,
                          int* __restrict__ offs, int* __restrict__ gbase){
  __shared__ int wsum[16];
  __shared__ int base_sh;
  int t = threadIdx.x, lane = t & 63, w = t >> 6;
  int i = blockIdx.x * 1024 + t;
  int v = (i < n) ? cnt[i] : 0;
  int x = v;
#pragma unroll
  for (int o = 1; o < 64; o <<= 1){
    int y = __shfl_up(x, o, 64);
    if (lane >= o) x += y;
  }
  if (lane == 63) wsum[w] = x;
  __syncthreads();
  if (t == 0){
    int tot = 0;
    for (int k = 0; k < 16; ++k){ int c = wsum[k]; wsum[k] = tot; tot += c; }
    base_sh = atomicAdd(gbase, tot);
  }
  __syncthreads();
  if (i < n) offs[i] = base_sh + wsum[w] + x - v;
}

// atomic-free fills: position known, pure gather+scatter (2 edges/thread)
__global__ void k_fill2_na(const int* __restrict__ src, const int* __restrict__ dst,
                           const int* __restrict__ offsA, const int* __restrict__ posA,
                           int* __restrict__ csrA,
                           const int* __restrict__ offsB, const int* __restrict__ posB,
                           int* __restrict__ csrB, int E){
  int t = blockIdx.x * 256 + threadIdx.x;
  int T = gridDim.x * 256;
  int k0 = t, k1 = t + T;
  bool b0 = k0 < E, b1 = k1 < E;
  int s0 = 0, d0 = 0, s1 = 0, d1 = 0, p0 = 0, q0 = 0, p1 = 0, q1 = 0;
  if (b0){ s0 = src[k0]; d0 = dst[k0]; p0 = posA[k0]; q0 = posB[k0]; }
  if (b1){ s1 = src[k1]; d1 = dst[k1]; p1 = posA[k1]; q1 = posB[k1]; }
  int oa0 = 0, ob0 = 0, oa1 = 0, ob1 = 0;
  if (b0){ oa0 = offsA[d0]; ob0 = offsB[s0]; }
  if (b1){ oa1 = offsA[d1]; ob1 = offsB[s1]; }
  if (b0){ csrA[oa0 + p0] = s0; csrB[ob0 + q0] = d0; }
  if (b1){ csrA[oa1 + p1] = s1; csrB[ob1 + q1] = d1; }
}
__global__ void k_fill_na(const int* __restrict__ src, const int* __restrict__ dst,
                          const int* __restrict__ offs, const int* __restrict__ pos,
                          int* __restrict__ csr, int E){
  int t = blockIdx.x * 256 + threadIdx.x;
  int T = gridDim.x * 256;
  int k0 = t, k1 = t + T;
  bool b0 = k0 < E, b1 = k1 < E;
  int s0 = 0, d0 = 0, p0 = 0, s1 = 0, d1 = 0, p1 = 0;
  if (b0){ s0 = src[k0]; d0 = dst[k0]; p0 = pos[k0]; }
  if (b1){ s1 = src[k1]; d1 = dst[k1]; p1 = pos[k1]; }
  int o0 = 0, o1 = 0;
  if (b0) o0 = offs[d0];
  if (b1) o1 = offs[d1];
  if (b0) csr[o0 + p0] = s0;
  if (b1) csr[o1 + p1] = s1;
}

// ============ fused GATv2 aggregation: 16 lanes/edge, 4 edges per wave ============
__global__ void k_gat(const int* __restrict__ offs, const int* __restrict__ cnt,
                      const int* __restrict__ csr_src,
                      const bf16* __restrict__ fs, const bf16* __restrict__ fd,
                      const float* __restrict__ attn, const float* __restrict__ bias,
                      float* __restrict__ out, int os, int oo,
                      const float* __restrict__ res, int rs, int ro, int n){
  int d = blockIdx.x * 4 + (threadIdx.x >> 6);
  if (d >= n) return;
  int lane = threadIdx.x & 63;
  int g = lane >> 4, l16 = lane & 15;
  short4v dv = *(const short4v*)(fd + (size_t)d * 64 + 4 * l16);
  float fd0 = b2f(dv[0]), fd1 = b2f(dv[1]), fd2 = b2f(dv[2]), fd3 = b2f(dv[3]);
  float4 a4 = *(const float4*)(attn + 4 * l16);
  float acc0 = 0.f, acc1 = 0.f, acc2 = 0.f, acc3 = 0.f, den = 0.f;
  int idx0 = offs[d], end = idx0 + cnt[d];
  for (int idx = idx0; idx < end; idx += 4){
    int e = idx + g;
    bool valid = e < end;
    int s = csr_src[valid ? e : idx];
    short4v sv = *(const short4v*)(fs + (size_t)s * 64 + 4 * l16);
    float f0 = b2f(sv[0]), f1 = b2f(sv[1]), f2 = b2f(sv[2]), f3 = b2f(sv[3]);
    float v0 = f0 + fd0; v0 = (v0 > 0.f ? v0 : 0.2f * v0) * a4.x;
    float v1 = f1 + fd1; v1 = (v1 > 0.f ? v1 : 0.2f * v1) * a4.y;
    float v2 = f2 + fd2; v2 = (v2 > 0.f ? v2 : 0.2f * v2) * a4.z;
    float v3 = f3 + fd3; v3 = (v3 > 0.f ? v3 : 0.2f * v3) * a4.w;
    float tt = (v0 + v1) + (v2 + v3);
#pragma unroll
    for (int o = 1; o < 16; o <<= 1) tt += __shfl_xor(tt, o, 64);
    float ex = valid ? __expf(tt) : 0.f;
    acc0 += ex * f0; acc1 += ex * f1; acc2 += ex * f2; acc3 += ex * f3;
    den += ex;
  }
#pragma unroll
  for (int o = 16; o < 64; o <<= 1){
    acc0 += __shfl_xor(acc0, o, 64); acc1 += __shfl_xor(acc1, o, 64);
    acc2 += __shfl_xor(acc2, o, 64); acc3 += __shfl_xor(acc3, o, 64);
    den  += __shfl_xor(den, o, 64);
  }
  if (g == 0){
    float4 b4 = *(const float4*)(bias + 4 * l16);
    float inv = (den > 0.f) ? 1.f / den : 0.f;
    float o0 = acc0 * inv + b4.x, o1 = acc1 * inv + b4.y;
    float o2 = acc2 * inv + b4.z, o3 = acc3 * inv + b4.w;
    if (res){
      float4 r4 = *(const float4*)(res + (size_t)d * rs + ro + 4 * l16);
      o0 += r4.x; o1 += r4.y; o2 += r4.z; o3 += r4.w;
    }
    *(float4*)(out + (size_t)d * os + oo + 4 * l16) = make_float4(o0, o1, o2, o3);
  }
}

// ---- collapse attention-gate MLP: v = W1@W2 (per l,i), c = b1@W2 + b2 ----
__global__ void k_attvec(const float* __restrict__ W1, const float* __restrict__ b1,
                         const float* __restrict__ W2, const float* __restrict__ b2,
                         float* __restrict__ vvec, float* __restrict__ cs){
  int t = threadIdx.x;
  int li = t >> 7, r = t & 127;
  float acc = 0.f;
  for (int c = 0; c < 128; ++c)
    acc += W1[(size_t)(li * 128 + r) * 128 + c] * W2[li * 128 + c];
  vvec[li * 128 + r] = acc;
  if (r == 0){
    float cacc = b2[li];
    for (int c = 0; c < 128; ++c)
      cacc += b1[li * 128 + c] * W2[li * 128 + c];
    cs[li] = cacc;
  }
}

// ---- gate z-scores + per-block partial sums for BatchNorm ----
__global__ void k_gate_z(const float* __restrict__ hu_all, int l,
                         const float* __restrict__ p, const float* __restrict__ q,
                         const float* __restrict__ vvec, const float* __restrict__ cs,
                         float* __restrict__ z1, float* __restrict__ z2,
                         float* __restrict__ bsums, int n){
  __shared__ float part[4][4];
  int w = threadIdx.x >> 6, j = threadIdx.x & 63;
  int nidx = blockIdx.x * 4 + w;
  float lz1 = 0.f, lz2 = 0.f;
  if (nidx < n){
    const float* v1 = vvec + l * 256;
    const float* v2 = vvec + l * 256 + 128;
    float h  = hu_all[(size_t)nidx * 192 + l * 64 + j];
    float pv = p[(size_t)nidx * 64 + j];
    float qv = q[(size_t)nidx * 64 + j];
    float t1 = wave_sum(h * v1[j] + pv * v1[64 + j]);
    float t2 = wave_sum(h * v2[j] + qv * v2[64 + j]);
    if (j == 0){
      lz1 = t1 + cs[l * 2 + 0];
      lz2 = t2 + cs[l * 2 + 1];
      z1[nidx] = lz1;
      z2[nidx] = lz2;
    }
  }
  if (j == 0){
    part[w][0] = lz1; part[w][1] = lz1 * lz1;
    part[w][2] = lz2; part[w][3] = lz2 * lz2;
  }
  __syncthreads();
  if (threadIdx.x < 4)
    bsums[(size_t)blockIdx.x * 4 + threadIdx.x] =
        part[0][threadIdx.x] + part[1][threadIdx.x] +
        part[2][threadIdx.x] + part[3][threadIdx.x];
}

// ---- BN reduce stage 1: 128 blocks grid-stride -> gpart[128][4] ----
__global__ void k_bn_part(const float* __restrict__ bsums, int nb,
                          double* __restrict__ gpart){
  __shared__ double sh[256];
  int c = threadIdx.x & 3, r0 = blockIdx.x * 64 + (threadIdx.x >> 2);
  double acc = 0.0;
  for (int i = r0; i < nb; i += gridDim.x * 64)
    acc += (double)bsums[(size_t)i * 4 + c];
  sh[threadIdx.x] = acc;
  __syncthreads();
  for (int s = 128; s >= 4; s >>= 1){
    if (threadIdx.x < s) sh[threadIdx.x] += sh[threadIdx.x + s];
    __syncthreads();
  }
  if (threadIdx.x < 4) gpart[(size_t)blockIdx.x * 4 + threadIdx.x] = sh[threadIdx.x];
}

// ---- BN reduce stage 2: single block over 128 partials -> sums[4] ----
__global__ void k_bn_final(const double* __restrict__ gpart, int nbk,
                           double* __restrict__ sums){
  __shared__ double sh[256];
  int c = threadIdx.x & 3, k0 = threadIdx.x >> 2;
  double acc = 0.0;
  for (int i = k0; i < nbk; i += 64) acc += gpart[(size_t)i * 4 + c];
  sh[threadIdx.x] = acc;
  __syncthreads();
  for (int s = 128; s >= 4; s >>= 1){
    if (threadIdx.x < s) sh[threadIdx.x] += sh[threadIdx.x + s];
    __syncthreads();
  }
  if (threadIdx.x < 4) sums[threadIdx.x] = sh[threadIdx.x];
}

// ---- BN + lrelu(0.01) + softmax gate + residual combine ----
__global__ void k_gate_combine(float* __restrict__ hu_all, int l,
                               const float* __restrict__ p, const float* __restrict__ q,
                               const float* __restrict__ z1, const float* __restrict__ z2,
                               const double* __restrict__ sums, int n){
  int idx = blockIdx.x * 256 + threadIdx.x;
  if (idx >= n * 64) return;
  int r = idx >> 6, j = idx & 63;
  double invn = 1.0 / (double)n;
  double mu1 = sums[0] * invn, mu2 = sums[2] * invn;
  float var1 = (float)(sums[1] * invn - mu1 * mu1);
  float var2 = (float)(sums[3] * invn - mu2 * mu2);
  float rs1 = rsqrtf(var1 + 1e-5f), rs2 = rsqrtf(var2 + 1e-5f);
  float a1 = (z1[r] - (float)mu1) * rs1;
  float a2 = (z2[r] - (float)mu2) * rs2;
  a1 = a1 > 0.f ? a1 : 0.01f * a1;
  a2 = a2 > 0.f ? a2 : 0.01f * a2;
  float mx = fmaxf(a1, a2);
  float e1 = __expf(a1 - mx), e2 = __expf(a2 - mx);
  float inv = 1.f / (e1 + e2);
  float out = (e1 * inv) * p[idx] + (e2 * inv) * q[idx]
            + hu_all[(size_t)r * 192 + l * 64 + j];
  hu_all[(size_t)r * 192 + (l + 1) * 64 + j] = out;
}

// ---- final scoring: 4 pairs per wave (16 lanes each), float4 loads ----
__global__ void k_score(const int* __restrict__ pu, const int* __restrict__ pi,
                        const int* __restrict__ nu, const int* __restrict__ ni,
                        const float* __restrict__ hu_all, const float* __restrict__ hi_all,
                        float* __restrict__ out, int EP){
  int gw = blockIdx.x * 4 + (threadIdx.x >> 6);
  int sub = (threadIdx.x >> 4) & 3, l16 = threadIdx.x & 15;
  int k = gw * 4 + sub;
  if (k >= 2 * EP) return;
  int u, i;
  if (k < EP){ u = pu[k]; i = pi[k]; } else { u = nu[k - EP]; i = ni[k - EP]; }
  const float4* hu = (const float4*)(hu_all + (size_t)u * 192);
  const float4* hi = (const float4*)(hi_all + (size_t)i * 192);
  float acc = 0.f;
#pragma unroll
  for (int t = 0; t < 3; ++t){
    float4 a = hu[l16 + 16 * t];
    float4 b = hi[l16 + 16 * t];
    acc += a.x * b.x + a.y * b.y + a.z * b.z + a.w * b.w;
  }
#pragma unroll
  for (int o = 8; o > 0; o >>= 1) acc += __shfl_xor(acc, o, 64);
  if (l16 == 0) out[k] = acc;
}

extern "C" void kernel_launch(void* const* d_in, const int* in_sizes, int n_in,
                              void* d_out, int out_size, void* d_ws, size_t ws_size,
                              hipStream_t stream) {
  const int*   rate_src  = (const int*)  d_in[0];
  const int*   rate_dst  = (const int*)  d_in[1];
  const int*   trust_src = (const int*)  d_in[2];
  const int*   trust_dst = (const int*)  d_in[3];
  const int*   pos_u     = (const int*)  d_in[4];
  const int*   pos_i     = (const int*)  d_in[5];
  const int*   neg_u     = (const int*)  d_in[6];
  const int*   neg_i     = (const int*)  d_in[7];
  const float* eu        = (const float*)d_in[8];
  const float* ei        = (const float*)d_in[9];
  const float* rate_W    = (const float*)d_in[10];
  const float* rate_b    = (const float*)d_in[11];
  const float* rate_attn = (const float*)d_in[12];
  const float* rate_bias = (const float*)d_in[13];
  const float* rb_W      = (const float*)d_in[14];
  const float* rb_b      = (const float*)d_in[15];
  const float* rb_attn   = (const float*)d_in[16];
  const float* rb_bias   = (const float*)d_in[17];
  const float* tr_W      = (const float*)d_in[18];
  const float* tr_b      = (const float*)d_in[19];
  const float* tr_attn   = (const float*)d_in[20];
  const float* tr_bias   = (const float*)d_in[21];
  const float* attW1     = (const float*)d_in[22];
  const float* attb1     = (const float*)d_in[23];
  const float* attW2     = (const float*)d_in[24];
  const float* attb2     = (const float*)d_in[25];

  const int ER = in_sizes[0];
  const int ET = in_sizes[2];
  const int EP = in_sizes[4];
  const int NU = in_sizes[8] / 64;
  const int NI = in_sizes[9] / 64;

  // ---- workspace layout (aliasing: pos arrays in table region, NI tables in p) ----
  float* ws = (float*)d_ws;
  float*  hu_all = ws;                                   // NU*192 f32
  float*  hi_all = hu_all + (size_t)NU * 192;            // NI*192
  float*  p      = hi_all + (size_t)NI * 192;            // NU*64 f32
  float*  q      = p + (size_t)NU * 64;                  // NU*64 f32
  bf16*   tb     = (bf16*)(q + (size_t)NU * 64);         // NU*256 bf16 (4 NU-tables)
  bf16*   fsA    = tb;                                   // NU*64
  bf16*   fdB    = tb + (size_t)NU * 64;                 // NU*64
  bf16*   fsC    = tb + (size_t)NU * 128;                // NU*64
  bf16*   fdC    = tb + (size_t)NU * 192;                // NU*64
  bf16*   fdA    = (bf16*)p;                             // NI*64 (alias: dead before p written)
  bf16*   fsB    = (bf16*)p + (size_t)NI * 64;           // NI*64 (alias)
  int*    posA   = (int*)fsA;                            // ER ints (alias: CSR build phase)
  int*    posB   = (int*)fdB;                            // ER ints
  int*    posC   = (int*)fsC;                            // ET ints
  float*  z1     = (float*)(tb + (size_t)NU * 256);      // NU
  float*  z2     = z1 + NU;                              // NU
  float*  bsums  = z2 + NU;                              // cdiv(NU,4)*4
  float*  vvec   = bsums + (size_t)(((NU + 3) / 4) * 4); // 512
  float*  cs     = vvec + 512;                           // 4
  double* sums   = (double*)(((uintptr_t)(cs + 4) + 15) & ~(uintptr_t)15); // 4
  double* gpart  = sums + 4;                             // 128*4
  short*  Whi    = (short*)(gpart + 512);                // 12*4096
  short*  Wlo    = Whi + 12 * 4096;                      // 12*4096
  int*    iw     = (int*)(Wlo + 12 * 4096);
  int*    cntA   = iw;                 // NI
  int*    cntB   = cntA + NI;          // NU
  int*    cntC   = cntB + NU;          // NU
  int*    gbase  = cntC + NU;          // 4 (3 used)
  int*    offsA  = gbase + 4;          // NI
  int*    offsB  = offsA + NI;         // NU
  int*    offsC  = offsB + NU;         // NU
  int*    csrA   = offsC + NU;         // ER
  int*    csrB   = csrA + ER;          // ER
  int*    csrC   = csrB + ER;          // ET

  auto cdiv = [](int a, int b){ return (a + b - 1) / b; };
  const int nbz = cdiv(NU, 4);

  // ---- one-time per call ----
  k_copy_in<<<cdiv(NU * 64, 256), 256, 0, stream>>>(eu, hu_all, NU, 192);
  k_copy_in<<<cdiv(NI * 64, 256), 256, 0, stream>>>(ei, hi_all, NI, 192);
  k_attvec<<<1, 512, 0, stream>>>(attW1, attb1, attW2, attb2, vvec, cs);
  k_wsplit<<<192, 256, 0, stream>>>(rate_W, rb_W, tr_W, Whi, Wlo);

  hipMemsetAsync(cntA, 0, (size_t)(NI + 2 * NU + 4) * 4, stream);
  k_hist2pos<<<cdiv(ER, 256), 256, 0, stream>>>(rate_src, rate_dst, cntA, cntB,
                                                posA, posB, ER);
  k_histpos<<<cdiv(ET, 256), 256, 0, stream>>>(trust_dst, cntC, posC, ET);
  k_scan_mb<<<cdiv(NI, 1024), 1024, 0, stream>>>(cntA, NI, offsA, gbase + 0);
  k_scan_mb<<<cdiv(NU, 1024), 1024, 0, stream>>>(cntB, NU, offsB, gbase + 1);
  k_scan_mb<<<cdiv(NU, 1024), 1024, 0, stream>>>(cntC, NU, offsC, gbase + 2);
  k_fill2_na<<<cdiv(ER, 512), 256, 0, stream>>>(rate_src, rate_dst,
      offsA, posA, csrA, offsB, posB, csrB, ER);
  k_fill_na<<<cdiv(ET, 512), 256, 0, stream>>>(trust_src, trust_dst,
      offsC, posC, csrC, ET);

  for (int l = 0; l < 2; ++l){
    // fused linears: NU side (4 outputs from one hu read), NI side (2 outputs)
    // m = rel*4 + l*2 + io; rel: rate=0, rb=1, tr=2
    k_linear_multi<<<cdiv(NU, 64), 256, 0, stream>>>(hu_all, 192, l * 64, NU, Whi, Wlo, 4,
        0 + l * 2 + 0, rate_b + (l * 2 + 0) * 64, fsA,     // rate src
        4 + l * 2 + 1, rb_b   + (l * 2 + 1) * 64, fdB,     // rb dst
        8 + l * 2 + 0, tr_b   + (l * 2 + 0) * 64, fsC,     // tr src
        8 + l * 2 + 1, tr_b   + (l * 2 + 1) * 64, fdC);    // tr dst
    k_linear_multi<<<cdiv(NI, 64), 256, 0, stream>>>(hi_all, 192, l * 64, NI, Whi, Wlo, 2,
        0 + l * 2 + 1, rate_b + (l * 2 + 1) * 64, fdA,     // rate dst
        4 + l * 2 + 0, rb_b   + (l * 2 + 0) * 64, fsB,     // rb src
        0, (const float*)nullptr, (bf16*)nullptr,
        0, (const float*)nullptr, (bf16*)nullptr);

    // rate GAT: users -> items, into hi_all block l+1 (+bias+residual)
    k_gat<<<cdiv(NI, 4), 256, 0, stream>>>(offsA, cntA, csrA, fsA, fdA,
        rate_attn + l * 64, rate_bias + l * 64,
        hi_all, 192, (l + 1) * 64, hi_all, 192, l * 64, NI);
    // rated-by GAT: items -> users -> q
    k_gat<<<cdiv(NU, 4), 256, 0, stream>>>(offsB, cntB, csrB, fsB, fdB,
        rb_attn + l * 64, rb_bias + l * 64,
        q, 64, 0, (const float*)nullptr, 0, 0, NU);
    // trust GAT: users -> users -> p (p overwrites fdA/fsB aliases: both dead now)
    k_gat<<<cdiv(NU, 4), 256, 0, stream>>>(offsC, cntC, csrC, fsC, fdC,
        tr_attn + l * 64, tr_bias + l * 64,
        p, 64, 0, (const float*)nullptr, 0, 0, NU);

    // attention gate + combine -> hu_all block l+1
    k_gate_z<<<nbz, 256, 0, stream>>>(hu_all, l, p, q, vvec, cs, z1, z2, bsums, NU);
    k_bn_part<<<128, 256, 0, stream>>>(bsums, nbz, gpart);
    k_bn_final<<<1, 256, 0, stream>>>(gpart, 128, sums);
    k_gate_combine<<<cdiv(NU * 64, 256), 256, 0, stream>>>(hu_all, l, p, q, z1, z2, sums, NU);
  }

  // ---- final scoring ----
  k_score<<<cdiv(2 * EP, 16), 256, 0, stream>>>(pos_u, pos_i, neg_u, neg_i,
      hu_all, hi_all, (float*)d_out, EP);
}